// Round 1
// 1470.615 us; speedup vs baseline: 1.1460x; 1.1460x over previous
//
#include <hip/hip_runtime.h>

#define DMM 768
#define DFF 3072
#define NH  12
#define HD  64
#define SQ  197
#define BA  64
#define NDD 732
#define MROWS (BA*SQ)   // 12608
#define MPAD  12672     // 99*128
#define PCOLS 224       // padded k-dim for P (7 x 32)
#define KS2   72        // Ks LDS stride (16B-aligned rows, free 2-way banking)
#define VTS   232       // Vt / P-read stride
#define QS    2304      // fused QKV row stride

typedef unsigned short u16;
typedef __bf16 bf16x8 __attribute__((ext_vector_type(8)));
typedef float  f32x4  __attribute__((ext_vector_type(4)));
typedef unsigned short us8 __attribute__((ext_vector_type(8)));

__device__ __forceinline__ float b2f(u16 u) {
    unsigned v = ((unsigned)u) << 16;
    float f; __builtin_memcpy(&f, &v, 4); return f;
}
__device__ __forceinline__ u16 f2b(float f) {
    unsigned v; __builtin_memcpy(&v, &f, 4);
    unsigned r = v + 0x7FFFu + ((v >> 16) & 1u);
    return (u16)(r >> 16);
}
__device__ __forceinline__ float gelu_exact(float x) {
    return 0.5f * x * (1.0f + erff(x * 0.70710678118654752f));
}
__device__ __forceinline__ void gload16(const u16* g, u16* l) {
    __builtin_amdgcn_global_load_lds(
        (const __attribute__((address_space(1))) unsigned int*)(g),
        (__attribute__((address_space(3))) unsigned int*)(l), 16, 0, 0);
}
__device__ __forceinline__ void hard_barrier() {
    asm volatile("s_waitcnt lgkmcnt(0)" ::: "memory");
    __builtin_amdgcn_s_barrier();
}

// ---------------- patch embed: x[B,14,14,DM] fp32 + cls -> h fp32 ---------
__global__ void patch_k(const float* __restrict__ x, const float* __restrict__ cls,
                        float* __restrict__ h) {
    long idx = (long)blockIdx.x * 256 + threadIdx.x;
    if (idx >= (long)MPAD * DMM) return;
    long r = idx / DMM; int c = (int)(idx % DMM);
    float v = 0.0f;
    if (r < MROWS) {
        int b = (int)(r / SQ), s = (int)(r % SQ);
        v = (s == 0) ? cls[c] : x[((long)b * 196 + (s - 1)) * DMM + c];
    }
    h[idx] = v;
}

// ---------------- final copy fp32 h -> fp32 out ---------------------------
__global__ void out_k(const float* __restrict__ h, float* __restrict__ out) {
    long idx = (long)blockIdx.x * 256 + threadIdx.x;
    if (idx < (long)MROWS * DMM) out[idx] = h[idx];
}

// ------- fused transpose+cast: in fp32 [K][N] -> out bf16 [N][K] ----------
__global__ __launch_bounds__(256) void tcast_k(const float* __restrict__ in,
                                               u16* __restrict__ out,
                                               int Kd, int Nd) {
    __shared__ float t[32][33];
    int k0 = blockIdx.x * 32, n0 = blockIdx.y * 32;
    int tx = threadIdx.x & 31, ty = threadIdx.x >> 5;   // ty 0..7
    #pragma unroll
    for (int i = 0; i < 4; ++i)
        t[tx][ty + 8 * i] = in[(long)(k0 + ty + 8 * i) * Nd + n0 + tx];
    __syncthreads();
    #pragma unroll
    for (int i = 0; i < 4; ++i)
        out[(long)(n0 + ty + 8 * i) * Kd + k0 + tx] = f2b(t[ty + 8 * i][tx]);
}

// ---------------- layernorm: h fp32 -> hn bf16 ----------------------------
__global__ __launch_bounds__(256) void ln_k(const float* __restrict__ h,
                                            const float* __restrict__ g,
                                            const float* __restrict__ b,
                                            u16* __restrict__ hn) {
    int row = blockIdx.x, tid = threadIdx.x;
    const float* hr = h + (long)row * DMM;
    float x0 = hr[tid], x1 = hr[tid + 256], x2 = hr[tid + 512];
    float s = x0 + x1 + x2, sq = x0 * x0 + x1 * x1 + x2 * x2;
    #pragma unroll
    for (int m = 32; m > 0; m >>= 1) {
        s  += __shfl_xor(s,  m, 64);
        sq += __shfl_xor(sq, m, 64);
    }
    __shared__ float ls[4], lq[4];
    int w = tid >> 6;
    if ((tid & 63) == 0) { ls[w] = s; lq[w] = sq; }
    __syncthreads();
    s  = ls[0] + ls[1] + ls[2] + ls[3];
    sq = lq[0] + lq[1] + lq[2] + lq[3];
    float mean = s * (1.0f / DMM);
    float var  = fmaxf(sq * (1.0f / DMM) - mean * mean, 0.0f);
    float rs = rsqrtf(var + 1e-12f);
    u16* hnr = hn + (long)row * DMM;
    hnr[tid]       = f2b((x0 - mean) * rs * g[tid]       + b[tid]);
    hnr[tid + 256] = f2b((x1 - mean) * rs * g[tid + 256] + b[tid + 256]);
    hnr[tid + 512] = f2b((x2 - mean) * rs * g[tid + 512] + b[tid + 512]);
}

// --------- concat bias [bq | 0 | bv] -> bqkv[2304] ------------------------
__global__ void bqkv_k(const float* __restrict__ bq, const float* __restrict__ bv,
                       float* __restrict__ out) {
    int i = blockIdx.x * 256 + threadIdx.x;
    if (i >= QS) return;
    out[i] = (i < 768) ? bq[i] : ((i < 1536) ? 0.0f : bv[i - 1536]);
}

// ---------------- GEMM: C[M][N] = A[M][K] @ B  (B given as BT[N][K]) ------
// 3-buffer, 2-ahead pipelined K-loop (raw s_barrier + counted vmcnt, T3/T4)
// + LDS-staged coalesced epilogue + XCD-chunked n-fastest block remap.
// EPI 0: out = acc + bias              -> bf16 outB
// EPI 1: out = gelu(acc + bias)        -> bf16 outB
// EPI 2: h   = h + (acc + bias) * lam  -> fp32 hio (in place)
template <int EPI>
__global__ __launch_bounds__(256) void gemm_bt(
    const u16* __restrict__ A, const u16* __restrict__ BT,
    const float* __restrict__ bias, u16* __restrict__ outB,
    float* __restrict__ hio, const float* __restrict__ lam,
    int K, int N) {
    __shared__ __align__(16) u16 pool[3 * 8192];   // 48 KB: 3 x (As 8KB | Bs 8KB)
    int tid = threadIdx.x;
    int w = tid >> 6, lane = tid & 63;
    int wr = w >> 1, wc = w & 1;
    int m16 = lane & 15;
    int kq  = (lane >> 4) * 8;
    int kq4 = (lane >> 4) * 4;

    // bijective XCD-chunked remap (m204); n-tile fastest inside a chunk so
    // co-XCD blocks reuse the same 128-row A panel in their private L2.
    int nwg = gridDim.x, bid = blockIdx.x;
    int qd = nwg >> 3, rm = nwg & 7;
    int xcd = bid & 7, seq = bid >> 3;
    int wg = (xcd < rm ? xcd * (qd + 1) : rm * (qd + 1) + (xcd - rm) * qd) + seq;
    int ntn = N >> 7;
    long m0 = (long)(wg / ntn) * 128;
    long n0 = (long)(wg % ntn) * 128;

    f32x4 acc[4][4] = {};

    int row_a = tid >> 2;          // 0..63
    int col_a = (tid & 3) * 8;     // 0,8,16,24
    const u16* gA0 = &A[(m0 + row_a) * (long)K + col_a];
    const u16* gA1 = &A[(m0 + 64 + row_a) * (long)K + col_a];
    const u16* gB0 = &BT[(n0 + row_a) * (long)K + col_a];
    const u16* gB1 = &BT[(n0 + 64 + row_a) * (long)K + col_a];
    int wo = w * 512;              // per-wave LDS chunk (u16 units)

    auto stage = [&](int k, u16* buf) {
        int k0 = k << 5;
        gload16(gA0 + k0, buf + wo);
        gload16(gA1 + k0, buf + 2048 + wo);
        gload16(gB0 + k0, buf + 4096 + wo);
        gload16(gB1 + k0, buf + 6144 + wo);
    };
    auto compute = [&](const u16* buf) {
        bf16x8 af[4], bf[4];
        #pragma unroll
        for (int i = 0; i < 4; ++i)
            af[i] = *(const bf16x8*)&buf[(wr * 64 + i * 16 + m16) * 32 + kq];
        #pragma unroll
        for (int j = 0; j < 4; ++j)
            bf[j] = *(const bf16x8*)&buf[4096 + (wc * 64 + j * 16 + m16) * 32 + kq];
        #pragma unroll
        for (int i = 0; i < 4; ++i)
            #pragma unroll
            for (int j = 0; j < 4; ++j)
                acc[i][j] = __builtin_amdgcn_mfma_f32_16x16x32_bf16(
                    af[i], bf[j], acc[i][j], 0, 0, 0);
    };

    const int nsteps = K >> 5;     // >= 24 for all shapes here
    stage(0, pool);
    stage(1, pool + 8192);
    u16* sb = pool + 16384;        // next stage target = buf (k+2)%3
    u16* cb = pool;                // compute source    = buf k%3
    for (int ks = 0; ks < nsteps - 2; ++ks) {
        // own stage(ks) done (4 newest = stage(ks+1) may stay in flight)
        asm volatile("s_waitcnt vmcnt(4) lgkmcnt(0)" ::: "memory");
        __builtin_amdgcn_s_barrier();
        stage(ks + 2, sb);         // overwrite buf (ks-1)%3: all waves past it
        compute(cb);
        sb = cb;
        cb = (cb == pool + 16384) ? pool : cb + 8192;
    }
    asm volatile("s_waitcnt vmcnt(4) lgkmcnt(0)" ::: "memory");
    __builtin_amdgcn_s_barrier();
    compute(cb);
    cb = (cb == pool + 16384) ? pool : cb + 8192;
    asm volatile("s_waitcnt vmcnt(0) lgkmcnt(0)" ::: "memory");
    __builtin_amdgcn_s_barrier();
    compute(cb);

    // ---- epilogue: stage C tile through LDS (fp32), coalesced global I/O --
    hard_barrier();                        // all waves done with staging LDS
    float* Cs = (float*)pool;              // [64][132] fp32 = 33792 B < 48 KB
    float bcol[4];
    #pragma unroll
    for (int j = 0; j < 4; ++j)
        bcol[j] = bias ? bias[n0 + wc * 64 + j * 16 + m16] : 0.0f;
    int et4 = tid * 4;
    int colr = et4 & 127;                  // same col group for every k chunk
    f32x4 lam4 = {};
    if (EPI == 2) lam4 = *(const f32x4*)&lam[n0 + colr];

    #pragma unroll
    for (int p = 0; p < 2; ++p) {          // two 64-row half-tiles
        if (p) hard_barrier();             // pass-0 readers done before overwrite
        if (wr == p) {
            #pragma unroll
            for (int i = 0; i < 4; ++i)
                #pragma unroll
                for (int j = 0; j < 4; ++j)
                    #pragma unroll
                    for (int r = 0; r < 4; ++r)
                        Cs[(i * 16 + kq4 + r) * 132 + wc * 64 + j * 16 + m16] =
                            acc[i][j][r] + bcol[j];
        }
        hard_barrier();
        #pragma unroll
        for (int k = 0; k < 8; ++k) {
            int e0 = k * 1024 + et4;       // linear elem in 64x128 half-tile
            int row = e0 >> 7;
            f32x4 v = *(const f32x4*)&Cs[row * 132 + colr];
            long gi = (m0 + p * 64 + row) * (long)N + n0 + colr;
            if (EPI == 0) {
                uint2 o;
                o.x = (unsigned)f2b(v[0]) | ((unsigned)f2b(v[1]) << 16);
                o.y = (unsigned)f2b(v[2]) | ((unsigned)f2b(v[3]) << 16);
                *(uint2*)&outB[gi] = o;
            } else if (EPI == 1) {
                uint2 o;
                o.x = (unsigned)f2b(gelu_exact(v[0])) | ((unsigned)f2b(gelu_exact(v[1])) << 16);
                o.y = (unsigned)f2b(gelu_exact(v[2])) | ((unsigned)f2b(gelu_exact(v[3])) << 16);
                *(uint2*)&outB[gi] = o;
            } else {
                f32x4 hv = *(f32x4*)&hio[gi];
                #pragma unroll
                for (int t = 0; t < 4; ++t) hv[t] += v[t] * lam4[t];
                *(f32x4*)&hio[gi] = hv;
            }
        }
    }
}

// ---------------- relative position bias index ----------------------------
__device__ __forceinline__ int relidx(int q, int k) {
    if (q == 0 && k == 0) return NDD - 1;
    if (k == 0) return NDD - 2;
    if (q == 0) return NDD - 3;
    int a = q - 1, c = k - 1;
    int dh = a / 14 - c / 14 + 13;
    int dw = a % 14 - c % 14 + 13;
    return dh * 27 + dw;
}

// -------- precompute bias[h][208][208] fp32 (0 outside valid range) -------
__global__ void bias_k(const float* __restrict__ rel, float* __restrict__ bias) {
    int idx = blockIdx.x * 256 + threadIdx.x;
    if (idx >= NH * 208 * 208) return;
    int hh = idx / (208 * 208);
    int r = (idx / 208) % 208, c = idx % 208;
    float v = 0.0f;
    if (r < SQ && c < SQ) v = rel[relidx(r, c) * NH + hh];
    bias[idx] = v;
}

// -------- attention part 1: S = QK^T * scale + bias, softmax -> P ---------
__global__ __launch_bounds__(256) void attn_qk(
    const u16* __restrict__ QKV, const float* __restrict__ bias,
    u16* __restrict__ P) {
    int bh = blockIdx.x;
    int b = bh / NH, hh = bh % NH;
    __shared__ u16 Ks[208 * KS2];
    int tid = threadIdx.x, w = tid >> 6, lane = tid & 63;
    long base = ((long)b * SQ) * QS + hh * HD;
    const u16* Qp = QKV;
    const u16* Kp = QKV + 768;
    u16* Pb = P + (long)bh * 208 * PCOLS;
    // zero P pad cols 208..223 (rows all written below)
    for (int idx = tid; idx < 208 * 16; idx += 256)
        Pb[(idx >> 4) * PCOLS + 208 + (idx & 15)] = 0;
    // stage K rows 0..207 (zeros beyond 196)
    for (int idx = tid; idx < 208 * 8; idx += 256) {
        int row = idx >> 3, dg = (idx & 7) * 8;
        us8 kv = {};
        if (row < SQ) kv = *(const us8*)&Kp[base + (long)row * QS + dg];
        *(us8*)&Ks[row * KS2 + dg] = kv;
    }
    __syncthreads();
    int m16 = lane & 15, quad = lane >> 4;
    int kq8 = quad * 8, q4 = quad * 4;
    const float* bh_bias = bias + (long)hh * 208 * 208;
    for (int t = w; t < 13; t += 4) {
        int m0 = t * 16;
        int qrow = m0 + m16; if (qrow > SQ - 1) qrow = SQ - 1;   // clamp pad rows
        bf16x8 a0 = *(const bf16x8*)&Qp[base + (long)qrow * QS + kq8];
        bf16x8 a1 = *(const bf16x8*)&Qp[base + (long)qrow * QS + 32 + kq8];
        f32x4 sc[13];
        #pragma unroll
        for (int n = 0; n < 13; ++n) {
            bf16x8 b0 = *(const bf16x8*)&Ks[(n * 16 + m16) * KS2 + kq8];
            bf16x8 b1 = *(const bf16x8*)&Ks[(n * 16 + m16) * KS2 + 32 + kq8];
            f32x4 z = {};
            z = __builtin_amdgcn_mfma_f32_16x16x32_bf16(a0, b0, z, 0, 0, 0);
            z = __builtin_amdgcn_mfma_f32_16x16x32_bf16(a1, b1, z, 0, 0, 0);
            sc[n] = z;
        }
        float mx[4] = {-3e38f, -3e38f, -3e38f, -3e38f};
        #pragma unroll
        for (int n = 0; n < 13; ++n) {
            int col = n * 16 + m16;
            bool valid = col < SQ;
            #pragma unroll
            for (int r = 0; r < 4; ++r) {
                float v = sc[n][r] * 0.125f + bh_bias[(m0 + q4 + r) * 208 + col];
                v = valid ? v : -3e38f;
                sc[n][r] = v;
                mx[r] = fmaxf(mx[r], v);
            }
        }
        #pragma unroll
        for (int r = 0; r < 4; ++r)
            #pragma unroll
            for (int msk = 1; msk < 16; msk <<= 1)
                mx[r] = fmaxf(mx[r], __shfl_xor(mx[r], msk, 64));
        float sum[4] = {0, 0, 0, 0};
        #pragma unroll
        for (int n = 0; n < 13; ++n)
            #pragma unroll
            for (int r = 0; r < 4; ++r) {
                float e = __expf(sc[n][r] - mx[r]);   // underflows to 0 when masked
                sc[n][r] = e;
                sum[r] += e;
            }
        #pragma unroll
        for (int r = 0; r < 4; ++r)
            #pragma unroll
            for (int msk = 1; msk < 16; msk <<= 1)
                sum[r] += __shfl_xor(sum[r], msk, 64);
        float inv[4];
        #pragma unroll
        for (int r = 0; r < 4; ++r) inv[r] = 1.0f / sum[r];
        #pragma unroll
        for (int n = 0; n < 13; ++n) {
            int col = n * 16 + m16;
            #pragma unroll
            for (int r = 0; r < 4; ++r)
                Pb[(m0 + q4 + r) * PCOLS + col] = f2b(sc[n][r] * inv[r]);
        }
    }
}

// -------- attention part 2: ctx = P @ V -----------------------------------
__global__ __launch_bounds__(256) void attn_pv(
    const u16* __restrict__ P, const u16* __restrict__ QKV,
    u16* __restrict__ ctx) {
    int bh = blockIdx.x;
    int b = bh / NH, hh = bh % NH;
    __shared__ u16 Vt[64 * VTS];   // Vt[d][k], zeros for k >= 197
    int tid = threadIdx.x, w = tid >> 6, lane = tid & 63;
    long base  = ((long)b * SQ) * QS + 1536 + hh * HD;
    long basec = ((long)b * SQ) * DMM + hh * HD;
    const u16* Vp = QKV;
    for (int idx = tid; idx < 224 * 8; idx += 256) {
        int row = idx >> 3, dg = (idx & 7) * 8;   // row = k index
        us8 vv = {};
        if (row < SQ) vv = *(const us8*)&Vp[base + (long)row * QS + dg];
        #pragma unroll
        for (int j = 0; j < 8; ++j) Vt[(dg + j) * VTS + row] = vv[j];
    }
    __syncthreads();
    const u16* Pb = P + (long)bh * 208 * PCOLS;
    int m16 = lane & 15, quad = lane >> 4;
    int kq8 = quad * 8, q4 = quad * 4;
    for (int t = w; t < 13; t += 4) {
        int m0 = t * 16;
        f32x4 co[4] = {};
        #pragma unroll
        for (int ks = 0; ks < 7; ++ks) {
            bf16x8 ap = *(const bf16x8*)&Pb[(m0 + m16) * PCOLS + ks * 32 + kq8];
            #pragma unroll
            for (int n = 0; n < 4; ++n) {
                bf16x8 bv = *(const bf16x8*)&Vt[(n * 16 + m16) * VTS + ks * 32 + kq8];
                co[n] = __builtin_amdgcn_mfma_f32_16x16x32_bf16(ap, bv, co[n], 0, 0, 0);
            }
        }
        #pragma unroll
        for (int n = 0; n < 4; ++n) {
            int col = n * 16 + m16;
            #pragma unroll
            for (int r = 0; r < 4; ++r) {
                int qr = m0 + q4 + r;
                if (qr < SQ) ctx[basec + (long)qr * DMM + col] = f2b(co[n][r]);
            }
        }
    }
}

// ---------------- host-side orchestration ---------------------------------
extern "C" void kernel_launch(void* const* d_in, const int* in_sizes, int n_in,
                              void* d_out, int out_size, void* d_ws, size_t ws_size,
                              hipStream_t stream) {
    const float* x    = (const float*)d_in[0];
    const float* cls  = (const float*)d_in[1];
    const float* g1   = (const float*)d_in[2];
    const float* b1   = (const float*)d_in[3];
    const float* Wq   = (const float*)d_in[4];
    const float* bq   = (const float*)d_in[5];
    const float* Wk   = (const float*)d_in[6];
    const float* Wv   = (const float*)d_in[7];
    const float* bv   = (const float*)d_in[8];
    const float* rel  = (const float*)d_in[9];
    const float* Wo   = (const float*)d_in[10];
    const float* bo   = (const float*)d_in[11];
    const float* lam1 = (const float*)d_in[12];
    const float* g2   = (const float*)d_in[13];
    const float* b2   = (const float*)d_in[14];
    const float* Wi   = (const float*)d_in[15];
    const float* bi   = (const float*)d_in[16];
    const float* Wmo  = (const float*)d_in[17];
    const float* bmo  = (const float*)d_in[18];
    const float* lam2 = (const float*)d_in[19];

    char* p = (char*)d_ws;
    auto alloc = [&](size_t bytes) -> void* {
        void* r = (void*)p;
        p += (bytes + 255) & ~(size_t)255;
        return r;
    };
    float* h     = (float*)alloc((size_t)MPAD * DMM * 4);
    u16*   hn    = (u16*)alloc((size_t)MPAD * DMM * 2);   // also reused as ctx
    u16*   qkvb  = (u16*)alloc((size_t)MPAD * QS * 2);    // fused Q|K|V
    u16*   ffh   = (u16*)alloc((size_t)MPAD * DFF * 2);   // also aliased as P
    u16*   WqkvT = (u16*)alloc((size_t)QS * DMM * 2);     // [2304][768]
    u16*   WoT   = (u16*)alloc((size_t)DMM * DMM * 2);
    u16*   WiT   = (u16*)alloc((size_t)DMM * DFF * 2);
    u16*   WmoT  = (u16*)alloc((size_t)DFF * DMM * 2);
    float* biasb = (float*)alloc((size_t)NH * 208 * 208 * 4);
    float* bqkv  = (float*)alloc((size_t)QS * 4);
    u16*   ctxb  = hn;   // alias: hn dead after QKV GEMM
    u16*   Pbuf  = ffh;  // alias: ffh dead during attention (71.6 MB <= 77.9 MB)

    patch_k<<<((long)MPAD * DMM + 255) / 256, 256, 0, stream>>>(x, cls, h);

    dim3 tg1(DMM / 32, DMM / 32);
    dim3 tg2(DMM / 32, DFF / 32);
    dim3 tg3(DFF / 32, DMM / 32);
    int gqkv = (MPAD / 128) * (QS / 128);    // 99*18 = 1782
    int g6   = (MPAD / 128) * (DMM / 128);   // 99*6  = 594
    int g24  = (MPAD / 128) * (DFF / 128);   // 99*24 = 2376

    for (int i = 0; i < 3; ++i) {
        size_t wofs  = (size_t)i * DMM * DMM;
        size_t wofs2 = (size_t)i * DMM * DFF;
        tcast_k<<<tg1, 256, 0, stream>>>(Wq + wofs, WqkvT,                 DMM, DMM);
        tcast_k<<<tg1, 256, 0, stream>>>(Wk + wofs, WqkvT + 768 * DMM,     DMM, DMM);
        tcast_k<<<tg1, 256, 0, stream>>>(Wv + wofs, WqkvT + 2 * 768 * DMM, DMM, DMM);
        tcast_k<<<tg1, 256, 0, stream>>>(Wo + wofs, WoT, DMM, DMM);
        tcast_k<<<tg2, 256, 0, stream>>>(Wi + wofs2, WiT, DMM, DFF);
        tcast_k<<<tg3, 256, 0, stream>>>(Wmo + wofs2, WmoT, DFF, DMM);
        bias_k<<<(NH * 208 * 208 + 255) / 256, 256, 0, stream>>>(rel + (size_t)i * NDD * NH, biasb);
        bqkv_k<<<(QS + 255) / 256, 256, 0, stream>>>(bq + i * DMM, bv + i * DMM, bqkv);

        ln_k<<<MPAD, 256, 0, stream>>>(h, g1 + i * DMM, b1 + i * DMM, hn);
        gemm_bt<0><<<gqkv, 256, 0, stream>>>(hn, WqkvT, bqkv, qkvb, nullptr, nullptr, DMM, QS);
        attn_qk<<<BA * NH, 256, 0, stream>>>(qkvb, biasb, Pbuf);
        attn_pv<<<BA * NH, 256, 0, stream>>>(Pbuf, qkvb, ctxb);
        gemm_bt<2><<<g6, 256, 0, stream>>>(ctxb, WoT, bo + i * DMM, nullptr, h, lam1 + i * DMM, DMM, DMM);
        ln_k<<<MPAD, 256, 0, stream>>>(h, g2 + i * DMM, b2 + i * DMM, hn);
        gemm_bt<1><<<g24, 256, 0, stream>>>(hn, WiT, bi + i * DFF, ffh, nullptr, nullptr, DMM, DFF);
        gemm_bt<2><<<g6, 256, 0, stream>>>(ffh, WmoT, bmo + i * DMM, nullptr, h, lam2 + i * DMM, DFF, DMM);
    }

    out_k<<<((long)MROWS * DMM + 255) / 256, 256, 0, stream>>>(h, (float*)d_out);
}

// Round 2
// 1383.055 us; speedup vs baseline: 1.2185x; 1.0633x over previous
//
#include <hip/hip_runtime.h>

#define DMM 768
#define DFF 3072
#define NH  12
#define HD  64
#define SQ  197
#define BA  64
#define NDD 732
#define MROWS (BA*SQ)   // 12608
#define MPAD  12672     // 99*128
#define PCOLS 224       // padded k-dim for P (7 x 32)
#define KS2   72        // Ks LDS stride (16B-aligned rows, free 2-way banking)
#define VTS   232       // Vt / P-read stride
#define QS    2304      // fused QKV row stride

typedef unsigned short u16;
typedef __bf16 bf16x8 __attribute__((ext_vector_type(8)));
typedef float  f32x4  __attribute__((ext_vector_type(4)));
typedef unsigned short us8 __attribute__((ext_vector_type(8)));

__device__ __forceinline__ float b2f(u16 u) {
    unsigned v = ((unsigned)u) << 16;
    float f; __builtin_memcpy(&f, &v, 4); return f;
}
__device__ __forceinline__ u16 f2b(float f) {
    unsigned v; __builtin_memcpy(&v, &f, 4);
    unsigned r = v + 0x7FFFu + ((v >> 16) & 1u);
    return (u16)(r >> 16);
}
__device__ __forceinline__ float gelu_exact(float x) {
    return 0.5f * x * (1.0f + erff(x * 0.70710678118654752f));
}
__device__ __forceinline__ void gload16(const u16* g, u16* l) {
    __builtin_amdgcn_global_load_lds(
        (const __attribute__((address_space(1))) unsigned int*)(g),
        (__attribute__((address_space(3))) unsigned int*)(l), 16, 0, 0);
}
__device__ __forceinline__ void hard_barrier() {
    asm volatile("s_waitcnt lgkmcnt(0)" ::: "memory");
    __builtin_amdgcn_s_barrier();
}

// ---------------- patch embed: x[B,14,14,DM] fp32 + cls -> h fp32 ---------
__global__ void patch_k(const float* __restrict__ x, const float* __restrict__ cls,
                        float* __restrict__ h) {
    long idx = (long)blockIdx.x * 256 + threadIdx.x;
    if (idx >= (long)MPAD * DMM) return;
    long r = idx / DMM; int c = (int)(idx % DMM);
    float v = 0.0f;
    if (r < MROWS) {
        int b = (int)(r / SQ), s = (int)(r % SQ);
        v = (s == 0) ? cls[c] : x[((long)b * 196 + (s - 1)) * DMM + c];
    }
    h[idx] = v;
}

// ---------------- final copy fp32 h -> fp32 out ---------------------------
__global__ void out_k(const float* __restrict__ h, float* __restrict__ out) {
    long idx = (long)blockIdx.x * 256 + threadIdx.x;
    if (idx < (long)MROWS * DMM) out[idx] = h[idx];
}

// ------- fused transpose+cast: in fp32 [K][N] -> out bf16 [N][K] ----------
__global__ __launch_bounds__(256) void tcast_k(const float* __restrict__ in,
                                               u16* __restrict__ out,
                                               int Kd, int Nd) {
    __shared__ float t[32][33];
    int k0 = blockIdx.x * 32, n0 = blockIdx.y * 32;
    int tx = threadIdx.x & 31, ty = threadIdx.x >> 5;   // ty 0..7
    #pragma unroll
    for (int i = 0; i < 4; ++i)
        t[tx][ty + 8 * i] = in[(long)(k0 + ty + 8 * i) * Nd + n0 + tx];
    __syncthreads();
    #pragma unroll
    for (int i = 0; i < 4; ++i)
        out[(long)(n0 + ty + 8 * i) * Kd + k0 + tx] = f2b(t[ty + 8 * i][tx]);
}

// ---------------- layernorm: h fp32 -> hn bf16 ----------------------------
__global__ __launch_bounds__(256) void ln_k(const float* __restrict__ h,
                                            const float* __restrict__ g,
                                            const float* __restrict__ b,
                                            u16* __restrict__ hn) {
    int row = blockIdx.x, tid = threadIdx.x;
    const float* hr = h + (long)row * DMM;
    float x0 = hr[tid], x1 = hr[tid + 256], x2 = hr[tid + 512];
    float s = x0 + x1 + x2, sq = x0 * x0 + x1 * x1 + x2 * x2;
    #pragma unroll
    for (int m = 32; m > 0; m >>= 1) {
        s  += __shfl_xor(s,  m, 64);
        sq += __shfl_xor(sq, m, 64);
    }
    __shared__ float ls[4], lq[4];
    int w = tid >> 6;
    if ((tid & 63) == 0) { ls[w] = s; lq[w] = sq; }
    __syncthreads();
    s  = ls[0] + ls[1] + ls[2] + ls[3];
    sq = lq[0] + lq[1] + lq[2] + lq[3];
    float mean = s * (1.0f / DMM);
    float var  = fmaxf(sq * (1.0f / DMM) - mean * mean, 0.0f);
    float rs = rsqrtf(var + 1e-12f);
    u16* hnr = hn + (long)row * DMM;
    hnr[tid]       = f2b((x0 - mean) * rs * g[tid]       + b[tid]);
    hnr[tid + 256] = f2b((x1 - mean) * rs * g[tid + 256] + b[tid + 256]);
    hnr[tid + 512] = f2b((x2 - mean) * rs * g[tid + 512] + b[tid + 512]);
}

// --------- concat bias [bq | 0 | bv] -> bqkv[2304] ------------------------
__global__ void bqkv_k(const float* __restrict__ bq, const float* __restrict__ bv,
                       float* __restrict__ out) {
    int i = blockIdx.x * 256 + threadIdx.x;
    if (i >= QS) return;
    out[i] = (i < 768) ? bq[i] : ((i < 1536) ? 0.0f : bv[i - 1536]);
}

// ---------------- GEMM: C[M][N] = A[M][K] @ B  (B given as BT[N][K]) ------
// 2-buffer counted-vmcnt pipeline (T3-minimum), unroll x2 so every LDS
// address is a compile-time immediate. LDS-staged coalesced epilogue,
// XCD-chunked n-fastest block remap.
// EPI 0: out = acc + bias              -> bf16 outB
// EPI 1: out = gelu(acc + bias)        -> bf16 outB
// EPI 2: h   = h + (acc + bias) * lam  -> fp32 hio (in place)
template <int EPI>
__global__ __launch_bounds__(256) void gemm_bt(
    const u16* __restrict__ A, const u16* __restrict__ BT,
    const float* __restrict__ bias, u16* __restrict__ outB,
    float* __restrict__ hio, const float* __restrict__ lam,
    int K, int N) {
    // 33792 B: K-loop uses 2 x 16 KB buffers; epilogue overlays [64][132] fp32
    __shared__ __align__(16) u16 pool[16896];
    int tid = threadIdx.x;
    int w = tid >> 6, lane = tid & 63;
    int wr = w >> 1, wc = w & 1;
    int m16 = lane & 15;
    int kq  = (lane >> 4) * 8;
    int kq4 = (lane >> 4) * 4;

    // bijective XCD-chunked remap (m204); n-tile fastest inside a chunk so
    // co-XCD blocks reuse the same 128-row A panel in their private L2.
    int nwg = gridDim.x, bid = blockIdx.x;
    int qd = nwg >> 3, rm = nwg & 7;
    int xcd = bid & 7, seq = bid >> 3;
    int wg = (xcd < rm ? xcd * (qd + 1) : rm * (qd + 1) + (xcd - rm) * qd) + seq;
    int ntn = N >> 7;
    long m0 = (long)(wg / ntn) * 128;
    long n0 = (long)(wg % ntn) * 128;

    f32x4 acc[4][4] = {};

    int row_a = tid >> 2;          // 0..63
    int col_a = (tid & 3) * 8;     // 0,8,16,24
    const u16* gA0 = &A[(m0 + row_a) * (long)K + col_a];
    const u16* gA1 = &A[(m0 + 64 + row_a) * (long)K + col_a];
    const u16* gB0 = &BT[(n0 + row_a) * (long)K + col_a];
    const u16* gB1 = &BT[(n0 + 64 + row_a) * (long)K + col_a];
    int wo = w * 512;              // per-wave LDS chunk (u16 units)

    u16* const b0 = pool;          // compile-time-constant buffer bases
    u16* const b1 = pool + 8192;

    auto stage = [&](int k, u16* buf) {
        int k0 = k << 5;
        gload16(gA0 + k0, buf + wo);
        gload16(gA1 + k0, buf + 2048 + wo);
        gload16(gB0 + k0, buf + 4096 + wo);
        gload16(gB1 + k0, buf + 6144 + wo);
    };
    auto compute = [&](const u16* buf) {
        bf16x8 af[4], bf[4];
        #pragma unroll
        for (int i = 0; i < 4; ++i)
            af[i] = *(const bf16x8*)&buf[(wr * 64 + i * 16 + m16) * 32 + kq];
        #pragma unroll
        for (int j = 0; j < 4; ++j)
            bf[j] = *(const bf16x8*)&buf[4096 + (wc * 64 + j * 16 + m16) * 32 + kq];
        #pragma unroll
        for (int i = 0; i < 4; ++i)
            #pragma unroll
            for (int j = 0; j < 4; ++j)
                acc[i][j] = __builtin_amdgcn_mfma_f32_16x16x32_bf16(
                    af[i], bf[j], acc[i][j], 0, 0, 0);
    };

    const int nsteps = K >> 5;     // even (24 or 96 here)
    stage(0, b0);
    for (int ks = 0; ks < nsteps - 2; ks += 2) {
        stage(ks + 1, b1);
        asm volatile("s_waitcnt vmcnt(4)" ::: "memory");  // stage(ks) landed
        __builtin_amdgcn_s_barrier();
        compute(b0);
        hard_barrier();            // all waves done reading b0
        stage(ks + 2, b0);
        asm volatile("s_waitcnt vmcnt(4)" ::: "memory");  // stage(ks+1) landed
        __builtin_amdgcn_s_barrier();
        compute(b1);
        hard_barrier();            // all waves done reading b1
    }
    // tail: steps nsteps-2 (staged into b0) and nsteps-1
    stage(nsteps - 1, b1);
    asm volatile("s_waitcnt vmcnt(4)" ::: "memory");
    __builtin_amdgcn_s_barrier();
    compute(b0);
    hard_barrier();
    asm volatile("s_waitcnt vmcnt(0)" ::: "memory");
    __builtin_amdgcn_s_barrier();
    compute(b1);

    // ---- epilogue: stage C tile through LDS (fp32), coalesced global I/O --
    hard_barrier();                        // all waves done with K-loop LDS
    float* Cs = (float*)pool;              // [64][132] fp32 = 33792 B
    float bcol[4];
    #pragma unroll
    for (int j = 0; j < 4; ++j)
        bcol[j] = bias ? bias[n0 + wc * 64 + j * 16 + m16] : 0.0f;
    int et4 = tid * 4;
    int colr = et4 & 127;                  // same col group for every k chunk
    f32x4 lam4 = {};
    if (EPI == 2) lam4 = *(const f32x4*)&lam[n0 + colr];

    #pragma unroll
    for (int p = 0; p < 2; ++p) {          // two 64-row half-tiles
        if (p) hard_barrier();             // pass-0 readers done before overwrite
        if (wr == p) {
            #pragma unroll
            for (int i = 0; i < 4; ++i)
                #pragma unroll
                for (int j = 0; j < 4; ++j)
                    #pragma unroll
                    for (int r = 0; r < 4; ++r)
                        Cs[(i * 16 + kq4 + r) * 132 + wc * 64 + j * 16 + m16] =
                            acc[i][j][r] + bcol[j];
        }
        hard_barrier();
        #pragma unroll
        for (int k = 0; k < 8; ++k) {
            int e0 = k * 1024 + et4;       // linear elem in 64x128 half-tile
            int row = e0 >> 7;
            f32x4 v = *(const f32x4*)&Cs[row * 132 + colr];
            long gi = (m0 + p * 64 + row) * (long)N + n0 + colr;
            if (EPI == 0) {
                uint2 o;
                o.x = (unsigned)f2b(v[0]) | ((unsigned)f2b(v[1]) << 16);
                o.y = (unsigned)f2b(v[2]) | ((unsigned)f2b(v[3]) << 16);
                *(uint2*)&outB[gi] = o;
            } else if (EPI == 1) {
                uint2 o;
                o.x = (unsigned)f2b(gelu_exact(v[0])) | ((unsigned)f2b(gelu_exact(v[1])) << 16);
                o.y = (unsigned)f2b(gelu_exact(v[2])) | ((unsigned)f2b(gelu_exact(v[3])) << 16);
                *(uint2*)&outB[gi] = o;
            } else {
                f32x4 hv = *(f32x4*)&hio[gi];
                #pragma unroll
                for (int t = 0; t < 4; ++t) hv[t] += v[t] * lam4[t];
                *(f32x4*)&hio[gi] = hv;
            }
        }
    }
}

// ---------------- relative position bias index ----------------------------
__device__ __forceinline__ int relidx(int q, int k) {
    if (q == 0 && k == 0) return NDD - 1;
    if (k == 0) return NDD - 2;
    if (q == 0) return NDD - 3;
    int a = q - 1, c = k - 1;
    int dh = a / 14 - c / 14 + 13;
    int dw = a % 14 - c % 14 + 13;
    return dh * 27 + dw;
}

// -------- precompute bias[h][208][208] fp32 (0 outside valid range) -------
__global__ void bias_k(const float* __restrict__ rel, float* __restrict__ bias) {
    int idx = blockIdx.x * 256 + threadIdx.x;
    if (idx >= NH * 208 * 208) return;
    int hh = idx / (208 * 208);
    int r = (idx / 208) % 208, c = idx % 208;
    float v = 0.0f;
    if (r < SQ && c < SQ) v = rel[relidx(r, c) * NH + hh];
    bias[idx] = v;
}

// -------- attention part 1: S = QK^T * scale + bias, softmax -> P ---------
__global__ __launch_bounds__(256) void attn_qk(
    const u16* __restrict__ QKV, const float* __restrict__ bias,
    u16* __restrict__ P) {
    int bh = blockIdx.x;
    int b = bh / NH, hh = bh % NH;
    __shared__ u16 Ks[208 * KS2];
    int tid = threadIdx.x, w = tid >> 6, lane = tid & 63;
    long base = ((long)b * SQ) * QS + hh * HD;
    const u16* Qp = QKV;
    const u16* Kp = QKV + 768;
    u16* Pb = P + (long)bh * 208 * PCOLS;
    // zero P pad cols 208..223 (rows all written below)
    for (int idx = tid; idx < 208 * 16; idx += 256)
        Pb[(idx >> 4) * PCOLS + 208 + (idx & 15)] = 0;
    // stage K rows 0..207 (zeros beyond 196)
    for (int idx = tid; idx < 208 * 8; idx += 256) {
        int row = idx >> 3, dg = (idx & 7) * 8;
        us8 kv = {};
        if (row < SQ) kv = *(const us8*)&Kp[base + (long)row * QS + dg];
        *(us8*)&Ks[row * KS2 + dg] = kv;
    }
    __syncthreads();
    int m16 = lane & 15, quad = lane >> 4;
    int kq8 = quad * 8, q4 = quad * 4;
    const float* bh_bias = bias + (long)hh * 208 * 208;
    for (int t = w; t < 13; t += 4) {
        int m0 = t * 16;
        int qrow = m0 + m16; if (qrow > SQ - 1) qrow = SQ - 1;   // clamp pad rows
        bf16x8 a0 = *(const bf16x8*)&Qp[base + (long)qrow * QS + kq8];
        bf16x8 a1 = *(const bf16x8*)&Qp[base + (long)qrow * QS + 32 + kq8];
        f32x4 sc[13];
        #pragma unroll
        for (int n = 0; n < 13; ++n) {
            bf16x8 b0 = *(const bf16x8*)&Ks[(n * 16 + m16) * KS2 + kq8];
            bf16x8 b1 = *(const bf16x8*)&Ks[(n * 16 + m16) * KS2 + 32 + kq8];
            f32x4 z = {};
            z = __builtin_amdgcn_mfma_f32_16x16x32_bf16(a0, b0, z, 0, 0, 0);
            z = __builtin_amdgcn_mfma_f32_16x16x32_bf16(a1, b1, z, 0, 0, 0);
            sc[n] = z;
        }
        float mx[4] = {-3e38f, -3e38f, -3e38f, -3e38f};
        #pragma unroll
        for (int n = 0; n < 13; ++n) {
            int col = n * 16 + m16;
            bool valid = col < SQ;
            #pragma unroll
            for (int r = 0; r < 4; ++r) {
                float v = sc[n][r] * 0.125f + bh_bias[(m0 + q4 + r) * 208 + col];
                v = valid ? v : -3e38f;
                sc[n][r] = v;
                mx[r] = fmaxf(mx[r], v);
            }
        }
        #pragma unroll
        for (int r = 0; r < 4; ++r)
            #pragma unroll
            for (int msk = 1; msk < 16; msk <<= 1)
                mx[r] = fmaxf(mx[r], __shfl_xor(mx[r], msk, 64));
        float sum[4] = {0, 0, 0, 0};
        #pragma unroll
        for (int n = 0; n < 13; ++n)
            #pragma unroll
            for (int r = 0; r < 4; ++r) {
                float e = __expf(sc[n][r] - mx[r]);   // underflows to 0 when masked
                sc[n][r] = e;
                sum[r] += e;
            }
        #pragma unroll
        for (int r = 0; r < 4; ++r)
            #pragma unroll
            for (int msk = 1; msk < 16; msk <<= 1)
                sum[r] += __shfl_xor(sum[r], msk, 64);
        float inv[4];
        #pragma unroll
        for (int r = 0; r < 4; ++r) inv[r] = 1.0f / sum[r];
        #pragma unroll
        for (int n = 0; n < 13; ++n) {
            int col = n * 16 + m16;
            #pragma unroll
            for (int r = 0; r < 4; ++r)
                Pb[(m0 + q4 + r) * PCOLS + col] = f2b(sc[n][r] * inv[r]);
        }
    }
}

// -------- attention part 2: ctx = P @ V -----------------------------------
__global__ __launch_bounds__(256) void attn_pv(
    const u16* __restrict__ P, const u16* __restrict__ QKV,
    u16* __restrict__ ctx) {
    int bh = blockIdx.x;
    int b = bh / NH, hh = bh % NH;
    __shared__ u16 Vt[64 * VTS];   // Vt[d][k], zeros for k >= 197
    int tid = threadIdx.x, w = tid >> 6, lane = tid & 63;
    long base  = ((long)b * SQ) * QS + 1536 + hh * HD;
    long basec = ((long)b * SQ) * DMM + hh * HD;
    const u16* Vp = QKV;
    for (int idx = tid; idx < 224 * 8; idx += 256) {
        int row = idx >> 3, dg = (idx & 7) * 8;   // row = k index
        us8 vv = {};
        if (row < SQ) vv = *(const us8*)&Vp[base + (long)row * QS + dg];
        #pragma unroll
        for (int j = 0; j < 8; ++j) Vt[(dg + j) * VTS + row] = vv[j];
    }
    __syncthreads();
    const u16* Pb = P + (long)bh * 208 * PCOLS;
    int m16 = lane & 15, quad = lane >> 4;
    int kq8 = quad * 8, q4 = quad * 4;
    for (int t = w; t < 13; t += 4) {
        int m0 = t * 16;
        f32x4 co[4] = {};
        #pragma unroll
        for (int ks = 0; ks < 7; ++ks) {
            bf16x8 ap = *(const bf16x8*)&Pb[(m0 + m16) * PCOLS + ks * 32 + kq8];
            #pragma unroll
            for (int n = 0; n < 4; ++n) {
                bf16x8 bv = *(const bf16x8*)&Vt[(n * 16 + m16) * VTS + ks * 32 + kq8];
                co[n] = __builtin_amdgcn_mfma_f32_16x16x32_bf16(ap, bv, co[n], 0, 0, 0);
            }
        }
        #pragma unroll
        for (int n = 0; n < 4; ++n) {
            int col = n * 16 + m16;
            #pragma unroll
            for (int r = 0; r < 4; ++r) {
                int qr = m0 + q4 + r;
                if (qr < SQ) ctx[basec + (long)qr * DMM + col] = f2b(co[n][r]);
            }
        }
    }
}

// ---------------- host-side orchestration ---------------------------------
extern "C" void kernel_launch(void* const* d_in, const int* in_sizes, int n_in,
                              void* d_out, int out_size, void* d_ws, size_t ws_size,
                              hipStream_t stream) {
    const float* x    = (const float*)d_in[0];
    const float* cls  = (const float*)d_in[1];
    const float* g1   = (const float*)d_in[2];
    const float* b1   = (const float*)d_in[3];
    const float* Wq   = (const float*)d_in[4];
    const float* bq   = (const float*)d_in[5];
    const float* Wk   = (const float*)d_in[6];
    const float* Wv   = (const float*)d_in[7];
    const float* bv   = (const float*)d_in[8];
    const float* rel  = (const float*)d_in[9];
    const float* Wo   = (const float*)d_in[10];
    const float* bo   = (const float*)d_in[11];
    const float* lam1 = (const float*)d_in[12];
    const float* g2   = (const float*)d_in[13];
    const float* b2   = (const float*)d_in[14];
    const float* Wi   = (const float*)d_in[15];
    const float* bi   = (const float*)d_in[16];
    const float* Wmo  = (const float*)d_in[17];
    const float* bmo  = (const float*)d_in[18];
    const float* lam2 = (const float*)d_in[19];

    char* p = (char*)d_ws;
    auto alloc = [&](size_t bytes) -> void* {
        void* r = (void*)p;
        p += (bytes + 255) & ~(size_t)255;
        return r;
    };
    float* h     = (float*)alloc((size_t)MPAD * DMM * 4);
    u16*   hn    = (u16*)alloc((size_t)MPAD * DMM * 2);   // also reused as ctx
    u16*   qkvb  = (u16*)alloc((size_t)MPAD * QS * 2);    // fused Q|K|V
    u16*   ffh   = (u16*)alloc((size_t)MPAD * DFF * 2);   // also aliased as P
    u16*   WqkvT = (u16*)alloc((size_t)QS * DMM * 2);     // [2304][768]
    u16*   WoT   = (u16*)alloc((size_t)DMM * DMM * 2);
    u16*   WiT   = (u16*)alloc((size_t)DMM * DFF * 2);
    u16*   WmoT  = (u16*)alloc((size_t)DFF * DMM * 2);
    float* biasb = (float*)alloc((size_t)NH * 208 * 208 * 4);
    float* bqkv  = (float*)alloc((size_t)QS * 4);
    u16*   ctxb  = hn;   // alias: hn dead after QKV GEMM
    u16*   Pbuf  = ffh;  // alias: ffh dead during attention (71.6 MB <= 77.9 MB)

    patch_k<<<((long)MPAD * DMM + 255) / 256, 256, 0, stream>>>(x, cls, h);

    dim3 tg1(DMM / 32, DMM / 32);
    dim3 tg2(DMM / 32, DFF / 32);
    dim3 tg3(DFF / 32, DMM / 32);
    int gqkv = (MPAD / 128) * (QS / 128);    // 99*18 = 1782
    int g6   = (MPAD / 128) * (DMM / 128);   // 99*6  = 594
    int g24  = (MPAD / 128) * (DFF / 128);   // 99*24 = 2376

    for (int i = 0; i < 3; ++i) {
        size_t wofs  = (size_t)i * DMM * DMM;
        size_t wofs2 = (size_t)i * DMM * DFF;
        tcast_k<<<tg1, 256, 0, stream>>>(Wq + wofs, WqkvT,                 DMM, DMM);
        tcast_k<<<tg1, 256, 0, stream>>>(Wk + wofs, WqkvT + 768 * DMM,     DMM, DMM);
        tcast_k<<<tg1, 256, 0, stream>>>(Wv + wofs, WqkvT + 2 * 768 * DMM, DMM, DMM);
        tcast_k<<<tg1, 256, 0, stream>>>(Wo + wofs, WoT, DMM, DMM);
        tcast_k<<<tg2, 256, 0, stream>>>(Wi + wofs2, WiT, DMM, DFF);
        tcast_k<<<tg3, 256, 0, stream>>>(Wmo + wofs2, WmoT, DFF, DMM);
        bias_k<<<(NH * 208 * 208 + 255) / 256, 256, 0, stream>>>(rel + (size_t)i * NDD * NH, biasb);
        bqkv_k<<<(QS + 255) / 256, 256, 0, stream>>>(bq + i * DMM, bv + i * DMM, bqkv);

        ln_k<<<MPAD, 256, 0, stream>>>(h, g1 + i * DMM, b1 + i * DMM, hn);
        gemm_bt<0><<<gqkv, 256, 0, stream>>>(hn, WqkvT, bqkv, qkvb, nullptr, nullptr, DMM, QS);
        attn_qk<<<BA * NH, 256, 0, stream>>>(qkvb, biasb, Pbuf);
        attn_pv<<<BA * NH, 256, 0, stream>>>(Pbuf, qkvb, ctxb);
        gemm_bt<2><<<g6, 256, 0, stream>>>(ctxb, WoT, bo + i * DMM, nullptr, h, lam1 + i * DMM, DMM, DMM);
        ln_k<<<MPAD, 256, 0, stream>>>(h, g2 + i * DMM, b2 + i * DMM, hn);
        gemm_bt<1><<<g24, 256, 0, stream>>>(hn, WiT, bi + i * DFF, ffh, nullptr, nullptr, DMM, DFF);
        gemm_bt<2><<<g6, 256, 0, stream>>>(ffh, WmoT, bmo + i * DMM, nullptr, h, lam2 + i * DMM, DFF, DMM);
    }

    out_k<<<((long)MROWS * DMM + 255) / 256, 256, 0, stream>>>(h, (float*)d_out);
}

// Round 3
// 1377.506 us; speedup vs baseline: 1.2234x; 1.0040x over previous
//
#include <hip/hip_runtime.h>

#define DMM 768
#define DFF 3072
#define NH  12
#define HD  64
#define SQ  197
#define BA  64
#define NDD 732
#define MROWS (BA*SQ)   // 12608
#define MPAD  12672     // 99*128
#define PCOLS 224       // padded k-dim for P (7 x 32)
#define KS2   72        // Ks LDS stride (16B-aligned rows, free 2-way banking)
#define VTS   232       // Vt / P-read stride
#define QS    2304      // fused QKV row stride
#define BIASN (NH*208*208)

typedef unsigned short u16;
typedef __bf16 bf16x8 __attribute__((ext_vector_type(8)));
typedef float  f32x4  __attribute__((ext_vector_type(4)));
typedef unsigned short us8 __attribute__((ext_vector_type(8)));

__device__ __forceinline__ float b2f(u16 u) {
    unsigned v = ((unsigned)u) << 16;
    float f; __builtin_memcpy(&f, &v, 4); return f;
}
__device__ __forceinline__ u16 f2b(float f) {
    unsigned v; __builtin_memcpy(&v, &f, 4);
    unsigned r = v + 0x7FFFu + ((v >> 16) & 1u);
    return (u16)(r >> 16);
}
__device__ __forceinline__ float gelu_exact(float x) {
    return 0.5f * x * (1.0f + erff(x * 0.70710678118654752f));
}
__device__ __forceinline__ void gload16(const u16* g, u16* l) {
    __builtin_amdgcn_global_load_lds(
        (const __attribute__((address_space(1))) unsigned int*)(g),
        (__attribute__((address_space(3))) unsigned int*)(l), 16, 0, 0);
}
__device__ __forceinline__ void hard_barrier() {
    asm volatile("s_waitcnt lgkmcnt(0)" ::: "memory");
    __builtin_amdgcn_s_barrier();
}

// ---------------- patch embed: x[B,14,14,DM] fp32 + cls -> h fp32 ---------
__global__ void patch_k(const float* __restrict__ x, const float* __restrict__ cls,
                        float* __restrict__ h) {
    long idx = (long)blockIdx.x * 256 + threadIdx.x;
    if (idx >= (long)MPAD * DMM) return;
    long r = idx / DMM; int c = (int)(idx % DMM);
    float v = 0.0f;
    if (r < MROWS) {
        int b = (int)(r / SQ), s = (int)(r % SQ);
        v = (s == 0) ? cls[c] : x[((long)b * 196 + (s - 1)) * DMM + c];
    }
    h[idx] = v;
}

// ---------------- final copy fp32 h -> fp32 out ---------------------------
__global__ void out_k(const float* __restrict__ h, float* __restrict__ out) {
    long idx = (long)blockIdx.x * 256 + threadIdx.x;
    if (idx < (long)MROWS * DMM) out[idx] = h[idx];
}

// ------- fused transpose+cast: in fp32 [K][N] -> out bf16 [N][K] ----------
__global__ __launch_bounds__(256) void tcast_k(const float* __restrict__ in,
                                               u16* __restrict__ out,
                                               int Kd, int Nd) {
    __shared__ float t[32][33];
    int k0 = blockIdx.x * 32, n0 = blockIdx.y * 32;
    int tx = threadIdx.x & 31, ty = threadIdx.x >> 5;   // ty 0..7
    #pragma unroll
    for (int i = 0; i < 4; ++i)
        t[tx][ty + 8 * i] = in[(long)(k0 + ty + 8 * i) * Nd + n0 + tx];
    __syncthreads();
    #pragma unroll
    for (int i = 0; i < 4; ++i)
        out[(long)(n0 + ty + 8 * i) * Kd + k0 + tx] = f2b(t[ty + 8 * i][tx]);
}

// ------- 4x batched 768x768 transpose+cast (one launch per layer) ---------
__global__ __launch_bounds__(256) void tcast4_k(
    const float* __restrict__ s0, const float* __restrict__ s1,
    const float* __restrict__ s2, const float* __restrict__ s3,
    u16* __restrict__ d0, u16* __restrict__ d1,
    u16* __restrict__ d2, u16* __restrict__ d3) {
    __shared__ float t[32][33];
    int z = blockIdx.z;
    const float* in = (z == 0) ? s0 : (z == 1) ? s1 : (z == 2) ? s2 : s3;
    u16* out = (z == 0) ? d0 : (z == 1) ? d1 : (z == 2) ? d2 : d3;
    int k0 = blockIdx.x * 32, n0 = blockIdx.y * 32;
    int tx = threadIdx.x & 31, ty = threadIdx.x >> 5;
    #pragma unroll
    for (int i = 0; i < 4; ++i)
        t[tx][ty + 8 * i] = in[(long)(k0 + ty + 8 * i) * DMM + n0 + tx];
    __syncthreads();
    #pragma unroll
    for (int i = 0; i < 4; ++i)
        out[(long)(n0 + ty + 8 * i) * DMM + k0 + tx] = f2b(t[ty + 8 * i][tx]);
}

// ---------------- layernorm: h fp32 -> hn bf16 ----------------------------
__global__ __launch_bounds__(256) void ln_k(const float* __restrict__ h,
                                            const float* __restrict__ g,
                                            const float* __restrict__ b,
                                            u16* __restrict__ hn) {
    int row = blockIdx.x, tid = threadIdx.x;
    const float* hr = h + (long)row * DMM;
    float x0 = hr[tid], x1 = hr[tid + 256], x2 = hr[tid + 512];
    float s = x0 + x1 + x2, sq = x0 * x0 + x1 * x1 + x2 * x2;
    #pragma unroll
    for (int m = 32; m > 0; m >>= 1) {
        s  += __shfl_xor(s,  m, 64);
        sq += __shfl_xor(sq, m, 64);
    }
    __shared__ float ls[4], lq[4];
    int w = tid >> 6;
    if ((tid & 63) == 0) { ls[w] = s; lq[w] = sq; }
    __syncthreads();
    s  = ls[0] + ls[1] + ls[2] + ls[3];
    sq = lq[0] + lq[1] + lq[2] + lq[3];
    float mean = s * (1.0f / DMM);
    float var  = fmaxf(sq * (1.0f / DMM) - mean * mean, 0.0f);
    float rs = rsqrtf(var + 1e-12f);
    u16* hnr = hn + (long)row * DMM;
    hnr[tid]       = f2b((x0 - mean) * rs * g[tid]       + b[tid]);
    hnr[tid + 256] = f2b((x1 - mean) * rs * g[tid + 256] + b[tid + 256]);
    hnr[tid + 512] = f2b((x2 - mean) * rs * g[tid + 512] + b[tid + 512]);
}

// ---------------- GEMM: C[M][N] = A[M][K] @ B  (B given as BT[N][K]) ------
// Distance-2 prefetch, 3 LDS buffers, ONE barrier per K-step:
//   vmcnt(4) -> s_barrier -> stage(k+2) -> compute(k)
// Buffer rotation statically unrolled x3 (nsteps % 3 == 0 for all shapes).
// LDS-staged coalesced epilogue, XCD-chunked n-fastest block remap.
// EPI 0: out = acc + bias              -> bf16 outB
// EPI 1: out = gelu(acc + bias)        -> bf16 outB
// EPI 2: h   = h + (acc + bias) * lam  -> fp32 hio (in place)
template <int EPI>
__global__ __launch_bounds__(256) void gemm_bt(
    const u16* __restrict__ A, const u16* __restrict__ BT,
    const float* __restrict__ bias, u16* __restrict__ outB,
    float* __restrict__ hio, const float* __restrict__ lam,
    int K, int N) {
    // 49152 B: 3 x 16 KB K-loop buffers; epilogue overlays [64][132] fp32
    __shared__ __align__(16) u16 pool[24576];
    int tid = threadIdx.x;
    int w = tid >> 6, lane = tid & 63;
    int wr = w >> 1, wc = w & 1;
    int m16 = lane & 15;
    int kq  = (lane >> 4) * 8;
    int kq4 = (lane >> 4) * 4;

    // bijective XCD-chunked remap (m204); n-tile fastest inside a chunk so
    // co-XCD blocks reuse the same 128-row A panel in their private L2.
    int nwg = gridDim.x, bid = blockIdx.x;
    int qd = nwg >> 3, rm = nwg & 7;
    int xcd = bid & 7, seq = bid >> 3;
    int wg = (xcd < rm ? xcd * (qd + 1) : rm * (qd + 1) + (xcd - rm) * qd) + seq;
    int ntn = N >> 7;
    long m0 = (long)(wg / ntn) * 128;
    long n0 = (long)(wg % ntn) * 128;

    f32x4 acc[4][4] = {};

    int row_a = tid >> 2;          // 0..63
    int col_a = (tid & 3) * 8;     // 0,8,16,24
    const u16* gA0 = &A[(m0 + row_a) * (long)K + col_a];
    const u16* gA1 = &A[(m0 + 64 + row_a) * (long)K + col_a];
    const u16* gB0 = &BT[(n0 + row_a) * (long)K + col_a];
    const u16* gB1 = &BT[(n0 + 64 + row_a) * (long)K + col_a];
    int wo = w * 512;              // per-wave LDS chunk (u16 units)

    u16* const b0 = pool;          // compile-time-constant buffer bases
    u16* const b1 = pool + 8192;
    u16* const b2 = pool + 16384;

    auto stage = [&](int k, u16* buf) {
        int k0 = k << 5;
        gload16(gA0 + k0, buf + wo);
        gload16(gA1 + k0, buf + 2048 + wo);
        gload16(gB0 + k0, buf + 4096 + wo);
        gload16(gB1 + k0, buf + 6144 + wo);
    };
    auto compute = [&](const u16* buf) {
        bf16x8 af[4], bf[4];
        #pragma unroll
        for (int i = 0; i < 4; ++i)
            af[i] = *(const bf16x8*)&buf[(wr * 64 + i * 16 + m16) * 32 + kq];
        #pragma unroll
        for (int j = 0; j < 4; ++j)
            bf[j] = *(const bf16x8*)&buf[4096 + (wc * 64 + j * 16 + m16) * 32 + kq];
        __builtin_amdgcn_s_setprio(1);
        #pragma unroll
        for (int i = 0; i < 4; ++i)
            #pragma unroll
            for (int j = 0; j < 4; ++j)
                acc[i][j] = __builtin_amdgcn_mfma_f32_16x16x32_bf16(
                    af[i], bf[j], acc[i][j], 0, 0, 0);
        __builtin_amdgcn_s_setprio(0);
    };

    const int nsteps = K >> 5;     // 24 or 96 here; nsteps % 3 == 0 required
    stage(0, b0);
    stage(1, b1);
    const int niter = nsteps / 3 - 1;
    for (int it = 0; it < niter; ++it) {
        int k = it * 3;
        // step k: b0. vmcnt(4): stage(k+1) may stay in flight, stage(k) done.
        asm volatile("s_waitcnt vmcnt(4)" ::: "memory");
        __builtin_amdgcn_s_barrier();
        stage(k + 2, b2);          // b2 last read at step k-1: all waves past it
        compute(b0);
        // step k+1: b1
        asm volatile("s_waitcnt vmcnt(4)" ::: "memory");
        __builtin_amdgcn_s_barrier();
        stage(k + 3, b0);
        compute(b1);
        // step k+2: b2
        asm volatile("s_waitcnt vmcnt(4)" ::: "memory");
        __builtin_amdgcn_s_barrier();
        stage(k + 4, b1);
        compute(b2);
    }
    // tail: steps nsteps-3 (b0), nsteps-2 (b1), nsteps-1 (b2)
    asm volatile("s_waitcnt vmcnt(4)" ::: "memory");
    __builtin_amdgcn_s_barrier();
    stage(nsteps - 1, b2);
    compute(b0);
    asm volatile("s_waitcnt vmcnt(4)" ::: "memory");
    __builtin_amdgcn_s_barrier();
    compute(b1);
    asm volatile("s_waitcnt vmcnt(0)" ::: "memory");
    __builtin_amdgcn_s_barrier();
    compute(b2);

    // ---- epilogue: stage C tile through LDS (fp32), coalesced global I/O --
    hard_barrier();                        // all waves done with K-loop LDS
    float* Cs = (float*)pool;              // [64][132] fp32 = 33792 B
    float bcol[4];
    #pragma unroll
    for (int j = 0; j < 4; ++j)
        bcol[j] = bias ? bias[n0 + wc * 64 + j * 16 + m16] : 0.0f;
    int et4 = tid * 4;
    int colr = et4 & 127;                  // same col group for every k chunk
    f32x4 lam4 = {};
    if (EPI == 2) lam4 = *(const f32x4*)&lam[n0 + colr];

    #pragma unroll
    for (int p = 0; p < 2; ++p) {          // two 64-row half-tiles
        if (p) hard_barrier();             // pass-0 readers done before overwrite
        if (wr == p) {
            #pragma unroll
            for (int i = 0; i < 4; ++i)
                #pragma unroll
                for (int j = 0; j < 4; ++j)
                    #pragma unroll
                    for (int r = 0; r < 4; ++r)
                        Cs[(i * 16 + kq4 + r) * 132 + wc * 64 + j * 16 + m16] =
                            acc[i][j][r] + bcol[j];
        }
        hard_barrier();
        #pragma unroll
        for (int k = 0; k < 8; ++k) {
            int e0 = k * 1024 + et4;       // linear elem in 64x128 half-tile
            int row = e0 >> 7;
            f32x4 v = *(const f32x4*)&Cs[row * 132 + colr];
            long gi = (m0 + p * 64 + row) * (long)N + n0 + colr;
            if (EPI == 0) {
                uint2 o;
                o.x = (unsigned)f2b(v[0]) | ((unsigned)f2b(v[1]) << 16);
                o.y = (unsigned)f2b(v[2]) | ((unsigned)f2b(v[3]) << 16);
                *(uint2*)&outB[gi] = o;
            } else if (EPI == 1) {
                uint2 o;
                o.x = (unsigned)f2b(gelu_exact(v[0])) | ((unsigned)f2b(gelu_exact(v[1])) << 16);
                o.y = (unsigned)f2b(gelu_exact(v[2])) | ((unsigned)f2b(gelu_exact(v[3])) << 16);
                *(uint2*)&outB[gi] = o;
            } else {
                f32x4 hv = *(f32x4*)&hio[gi];
                #pragma unroll
                for (int t = 0; t < 4; ++t) hv[t] += v[t] * lam4[t];
                *(f32x4*)&hio[gi] = hv;
            }
        }
    }
}

// ---------------- relative position bias index ----------------------------
__device__ __forceinline__ int relidx(int q, int k) {
    if (q == 0 && k == 0) return NDD - 1;
    if (k == 0) return NDD - 2;
    if (q == 0) return NDD - 3;
    int a = q - 1, c = k - 1;
    int dh = a / 14 - c / 14 + 13;
    int dw = a % 14 - c % 14 + 13;
    return dh * 27 + dw;
}

// -- precompute bias[h][208][208] fp32 + fused bqkv concat (one launch) ----
__global__ void bias_k(const float* __restrict__ rel, float* __restrict__ bias,
                       const float* __restrict__ bq, const float* __restrict__ bv,
                       float* __restrict__ bqkv) {
    int idx = blockIdx.x * 256 + threadIdx.x;
    if (idx < BIASN) {
        int hh = idx / (208 * 208);
        int r = (idx / 208) % 208, c = idx % 208;
        float v = 0.0f;
        if (r < SQ && c < SQ) v = rel[relidx(r, c) * NH + hh];
        bias[idx] = v;
    } else {
        int i = idx - BIASN;
        if (i < QS)
            bqkv[i] = (i < 768) ? bq[i] : ((i < 1536) ? 0.0f : bv[i - 1536]);
    }
}

// -------- attention part 1: S = QK^T * scale + bias, softmax -> P ---------
__global__ __launch_bounds__(256) void attn_qk(
    const u16* __restrict__ QKV, const float* __restrict__ bias,
    u16* __restrict__ P) {
    int bh = blockIdx.x;
    int b = bh / NH, hh = bh % NH;
    __shared__ u16 Ks[208 * KS2];
    int tid = threadIdx.x, w = tid >> 6, lane = tid & 63;
    long base = ((long)b * SQ) * QS + hh * HD;
    const u16* Qp = QKV;
    const u16* Kp = QKV + 768;
    u16* Pb = P + (long)bh * 208 * PCOLS;
    // zero P pad cols 208..223 (rows all written below)
    for (int idx = tid; idx < 208 * 16; idx += 256)
        Pb[(idx >> 4) * PCOLS + 208 + (idx & 15)] = 0;
    // stage K rows 0..207 (zeros beyond 196)
    for (int idx = tid; idx < 208 * 8; idx += 256) {
        int row = idx >> 3, dg = (idx & 7) * 8;
        us8 kv = {};
        if (row < SQ) kv = *(const us8*)&Kp[base + (long)row * QS + dg];
        *(us8*)&Ks[row * KS2 + dg] = kv;
    }
    __syncthreads();
    int m16 = lane & 15, quad = lane >> 4;
    int kq8 = quad * 8, q4 = quad * 4;
    const float* bh_bias = bias + (long)hh * 208 * 208;
    for (int t = w; t < 13; t += 4) {
        int m0 = t * 16;
        int qrow = m0 + m16; if (qrow > SQ - 1) qrow = SQ - 1;   // clamp pad rows
        bf16x8 a0 = *(const bf16x8*)&Qp[base + (long)qrow * QS + kq8];
        bf16x8 a1 = *(const bf16x8*)&Qp[base + (long)qrow * QS + 32 + kq8];
        f32x4 sc[13];
        #pragma unroll
        for (int n = 0; n < 13; ++n) {
            bf16x8 b0 = *(const bf16x8*)&Ks[(n * 16 + m16) * KS2 + kq8];
            bf16x8 b1 = *(const bf16x8*)&Ks[(n * 16 + m16) * KS2 + 32 + kq8];
            f32x4 z = {};
            z = __builtin_amdgcn_mfma_f32_16x16x32_bf16(a0, b0, z, 0, 0, 0);
            z = __builtin_amdgcn_mfma_f32_16x16x32_bf16(a1, b1, z, 0, 0, 0);
            sc[n] = z;
        }
        float mx[4] = {-3e38f, -3e38f, -3e38f, -3e38f};
        #pragma unroll
        for (int n = 0; n < 13; ++n) {
            int col = n * 16 + m16;
            bool valid = col < SQ;
            #pragma unroll
            for (int r = 0; r < 4; ++r) {
                float v = sc[n][r] * 0.125f + bh_bias[(m0 + q4 + r) * 208 + col];
                v = valid ? v : -3e38f;
                sc[n][r] = v;
                mx[r] = fmaxf(mx[r], v);
            }
        }
        #pragma unroll
        for (int r = 0; r < 4; ++r)
            #pragma unroll
            for (int msk = 1; msk < 16; msk <<= 1)
                mx[r] = fmaxf(mx[r], __shfl_xor(mx[r], msk, 64));
        float sum[4] = {0, 0, 0, 0};
        #pragma unroll
        for (int n = 0; n < 13; ++n)
            #pragma unroll
            for (int r = 0; r < 4; ++r) {
                float e = __expf(sc[n][r] - mx[r]);   // underflows to 0 when masked
                sc[n][r] = e;
                sum[r] += e;
            }
        #pragma unroll
        for (int r = 0; r < 4; ++r)
            #pragma unroll
            for (int msk = 1; msk < 16; msk <<= 1)
                sum[r] += __shfl_xor(sum[r], msk, 64);
        float inv[4];
        #pragma unroll
        for (int r = 0; r < 4; ++r) inv[r] = 1.0f / sum[r];
        #pragma unroll
        for (int n = 0; n < 13; ++n) {
            int col = n * 16 + m16;
            #pragma unroll
            for (int r = 0; r < 4; ++r)
                Pb[(m0 + q4 + r) * PCOLS + col] = f2b(sc[n][r] * inv[r]);
        }
    }
}

// -------- attention part 2: ctx = P @ V -----------------------------------
__global__ __launch_bounds__(256) void attn_pv(
    const u16* __restrict__ P, const u16* __restrict__ QKV,
    u16* __restrict__ ctx) {
    int bh = blockIdx.x;
    int b = bh / NH, hh = bh % NH;
    __shared__ u16 Vt[64 * VTS];   // Vt[d][k], zeros for k >= 197
    int tid = threadIdx.x, w = tid >> 6, lane = tid & 63;
    long base  = ((long)b * SQ) * QS + 1536 + hh * HD;
    long basec = ((long)b * SQ) * DMM + hh * HD;
    const u16* Vp = QKV;
    for (int idx = tid; idx < 224 * 8; idx += 256) {
        int row = idx >> 3, dg = (idx & 7) * 8;   // row = k index
        us8 vv = {};
        if (row < SQ) vv = *(const us8*)&Vp[base + (long)row * QS + dg];
        #pragma unroll
        for (int j = 0; j < 8; ++j) Vt[(dg + j) * VTS + row] = vv[j];
    }
    __syncthreads();
    const u16* Pb = P + (long)bh * 208 * PCOLS;
    int m16 = lane & 15, quad = lane >> 4;
    int kq8 = quad * 8, q4 = quad * 4;
    for (int t = w; t < 13; t += 4) {
        int m0 = t * 16;
        f32x4 co[4] = {};
        #pragma unroll
        for (int ks = 0; ks < 7; ++ks) {
            bf16x8 ap = *(const bf16x8*)&Pb[(m0 + m16) * PCOLS + ks * 32 + kq8];
            #pragma unroll
            for (int n = 0; n < 4; ++n) {
                bf16x8 bv = *(const bf16x8*)&Vt[(n * 16 + m16) * VTS + ks * 32 + kq8];
                co[n] = __builtin_amdgcn_mfma_f32_16x16x32_bf16(ap, bv, co[n], 0, 0, 0);
            }
        }
        #pragma unroll
        for (int n = 0; n < 4; ++n) {
            int col = n * 16 + m16;
            #pragma unroll
            for (int r = 0; r < 4; ++r) {
                int qr = m0 + q4 + r;
                if (qr < SQ) ctx[basec + (long)qr * DMM + col] = f2b(co[n][r]);
            }
        }
    }
}

// ---------------- host-side orchestration ---------------------------------
extern "C" void kernel_launch(void* const* d_in, const int* in_sizes, int n_in,
                              void* d_out, int out_size, void* d_ws, size_t ws_size,
                              hipStream_t stream) {
    const float* x    = (const float*)d_in[0];
    const float* cls  = (const float*)d_in[1];
    const float* g1   = (const float*)d_in[2];
    const float* b1   = (const float*)d_in[3];
    const float* Wq   = (const float*)d_in[4];
    const float* bq   = (const float*)d_in[5];
    const float* Wk   = (const float*)d_in[6];
    const float* Wv   = (const float*)d_in[7];
    const float* bv   = (const float*)d_in[8];
    const float* rel  = (const float*)d_in[9];
    const float* Wo   = (const float*)d_in[10];
    const float* bo   = (const float*)d_in[11];
    const float* lam1 = (const float*)d_in[12];
    const float* g2   = (const float*)d_in[13];
    const float* b2   = (const float*)d_in[14];
    const float* Wi   = (const float*)d_in[15];
    const float* bi   = (const float*)d_in[16];
    const float* Wmo  = (const float*)d_in[17];
    const float* bmo  = (const float*)d_in[18];
    const float* lam2 = (const float*)d_in[19];

    char* p = (char*)d_ws;
    auto alloc = [&](size_t bytes) -> void* {
        void* r = (void*)p;
        p += (bytes + 255) & ~(size_t)255;
        return r;
    };
    float* h     = (float*)alloc((size_t)MPAD * DMM * 4);
    u16*   hn    = (u16*)alloc((size_t)MPAD * DMM * 2);   // also reused as ctx
    u16*   qkvb  = (u16*)alloc((size_t)MPAD * QS * 2);    // fused Q|K|V
    u16*   ffh   = (u16*)alloc((size_t)MPAD * DFF * 2);   // also aliased as P
    u16*   WqkvT = (u16*)alloc((size_t)QS * DMM * 2);     // [2304][768]
    u16*   WoT   = (u16*)alloc((size_t)DMM * DMM * 2);
    u16*   WiT   = (u16*)alloc((size_t)DMM * DFF * 2);
    u16*   WmoT  = (u16*)alloc((size_t)DFF * DMM * 2);
    float* biasb = (float*)alloc((size_t)NH * 208 * 208 * 4);
    float* bqkv  = (float*)alloc((size_t)QS * 4);
    u16*   ctxb  = hn;   // alias: hn dead after QKV GEMM
    u16*   Pbuf  = ffh;  // alias: ffh dead during attention (71.6 MB <= 77.9 MB)

    patch_k<<<((long)MPAD * DMM + 255) / 256, 256, 0, stream>>>(x, cls, h);

    dim3 tg4(DMM / 32, DMM / 32, 4);
    dim3 tg2(DMM / 32, DFF / 32);
    dim3 tg3(DFF / 32, DMM / 32);
    int gqkv = (MPAD / 128) * (QS / 128);    // 99*18 = 1782
    int g6   = (MPAD / 128) * (DMM / 128);   // 99*6  = 594
    int g24  = (MPAD / 128) * (DFF / 128);   // 99*24 = 2376

    for (int i = 0; i < 3; ++i) {
        size_t wofs  = (size_t)i * DMM * DMM;
        size_t wofs2 = (size_t)i * DMM * DFF;
        tcast4_k<<<tg4, 256, 0, stream>>>(Wq + wofs, Wk + wofs, Wv + wofs, Wo + wofs,
                                          WqkvT, WqkvT + 768 * DMM,
                                          WqkvT + 2 * 768 * DMM, WoT);
        tcast_k<<<tg2, 256, 0, stream>>>(Wi + wofs2, WiT, DMM, DFF);
        tcast_k<<<tg3, 256, 0, stream>>>(Wmo + wofs2, WmoT, DFF, DMM);
        bias_k<<<(BIASN + QS + 255) / 256, 256, 0, stream>>>(
            rel + (size_t)i * NDD * NH, biasb, bq + i * DMM, bv + i * DMM, bqkv);

        ln_k<<<MPAD, 256, 0, stream>>>(h, g1 + i * DMM, b1 + i * DMM, hn);
        gemm_bt<0><<<gqkv, 256, 0, stream>>>(hn, WqkvT, bqkv, qkvb, nullptr, nullptr, DMM, QS);
        attn_qk<<<BA * NH, 256, 0, stream>>>(qkvb, biasb, Pbuf);
        attn_pv<<<BA * NH, 256, 0, stream>>>(Pbuf, qkvb, ctxb);
        gemm_bt<2><<<g6, 256, 0, stream>>>(ctxb, WoT, bo + i * DMM, nullptr, h, lam1 + i * DMM, DMM, DMM);
        ln_k<<<MPAD, 256, 0, stream>>>(h, g2 + i * DMM, b2 + i * DMM, hn);
        gemm_bt<1><<<g24, 256, 0, stream>>>(hn, WiT, bi + i * DFF, ffh, nullptr, nullptr, DMM, DFF);
        gemm_bt<2><<<g6, 256, 0, stream>>>(ffh, WmoT, bmo + i * DMM, nullptr, h, lam2 + i * DMM, DFF, DMM);
    }

    out_k<<<((long)MROWS * DMM + 255) / 256, 256, 0, stream>>>(h, (float*)d_out);
}

// Round 4
// 1352.862 us; speedup vs baseline: 1.2457x; 1.0182x over previous
//
#include <hip/hip_runtime.h>

#define DMM 768
#define DFF 3072
#define NH  12
#define HD  64
#define SQ  197
#define BA  64
#define NDD 732
#define MROWS (BA*SQ)   // 12608
#define MPAD  12800     // 50*256 (padded for 256-row tiles)
#define PCOLS 224       // padded k-dim for P (7 x 32)
#define KS2   72        // Ks LDS stride (16B-aligned rows, free 2-way banking)
#define VTS   232       // Vt / P-read stride
#define QS    2304      // fused QKV row stride
#define BIASN (NH*208*208)

typedef unsigned short u16;
typedef __bf16 bf16x8 __attribute__((ext_vector_type(8)));
typedef float  f32x4  __attribute__((ext_vector_type(4)));
typedef unsigned short us8 __attribute__((ext_vector_type(8)));

__device__ __forceinline__ float b2f(u16 u) {
    unsigned v = ((unsigned)u) << 16;
    float f; __builtin_memcpy(&f, &v, 4); return f;
}
__device__ __forceinline__ u16 f2b(float f) {
    unsigned v; __builtin_memcpy(&v, &f, 4);
    unsigned r = v + 0x7FFFu + ((v >> 16) & 1u);
    return (u16)(r >> 16);
}
__device__ __forceinline__ float gelu_exact(float x) {
    return 0.5f * x * (1.0f + erff(x * 0.70710678118654752f));
}
__device__ __forceinline__ void gload16(const u16* g, u16* l) {
    __builtin_amdgcn_global_load_lds(
        (const __attribute__((address_space(1))) unsigned int*)(g),
        (__attribute__((address_space(3))) unsigned int*)(l), 16, 0, 0);
}
__device__ __forceinline__ void hard_barrier() {
    asm volatile("s_waitcnt lgkmcnt(0)" ::: "memory");
    __builtin_amdgcn_s_barrier();
}

// ---------------- patch embed: x[B,14,14,DM] fp32 + cls -> h fp32 ---------
__global__ void patch_k(const float* __restrict__ x, const float* __restrict__ cls,
                        float* __restrict__ h) {
    long idx = (long)blockIdx.x * 256 + threadIdx.x;
    if (idx >= (long)MPAD * DMM) return;
    long r = idx / DMM; int c = (int)(idx % DMM);
    float v = 0.0f;
    if (r < MROWS) {
        int b = (int)(r / SQ), s = (int)(r % SQ);
        v = (s == 0) ? cls[c] : x[((long)b * 196 + (s - 1)) * DMM + c];
    }
    h[idx] = v;
}

// ---------------- final copy fp32 h -> fp32 out ---------------------------
__global__ void out_k(const float* __restrict__ h, float* __restrict__ out) {
    long idx = (long)blockIdx.x * 256 + threadIdx.x;
    if (idx < (long)MROWS * DMM) out[idx] = h[idx];
}

// ------- fused transpose+cast: in fp32 [K][N] -> out bf16 [N][K] ----------
__global__ __launch_bounds__(256) void tcast_k(const float* __restrict__ in,
                                               u16* __restrict__ out,
                                               int Kd, int Nd) {
    __shared__ float t[32][33];
    int k0 = blockIdx.x * 32, n0 = blockIdx.y * 32;
    int tx = threadIdx.x & 31, ty = threadIdx.x >> 5;   // ty 0..7
    #pragma unroll
    for (int i = 0; i < 4; ++i)
        t[tx][ty + 8 * i] = in[(long)(k0 + ty + 8 * i) * Nd + n0 + tx];
    __syncthreads();
    #pragma unroll
    for (int i = 0; i < 4; ++i)
        out[(long)(n0 + ty + 8 * i) * Kd + k0 + tx] = f2b(t[ty + 8 * i][tx]);
}

// ------- 4x batched 768x768 transpose+cast (one launch per layer) ---------
__global__ __launch_bounds__(256) void tcast4_k(
    const float* __restrict__ s0, const float* __restrict__ s1,
    const float* __restrict__ s2, const float* __restrict__ s3,
    u16* __restrict__ d0, u16* __restrict__ d1,
    u16* __restrict__ d2, u16* __restrict__ d3) {
    __shared__ float t[32][33];
    int z = blockIdx.z;
    const float* in = (z == 0) ? s0 : (z == 1) ? s1 : (z == 2) ? s2 : s3;
    u16* out = (z == 0) ? d0 : (z == 1) ? d1 : (z == 2) ? d2 : d3;
    int k0 = blockIdx.x * 32, n0 = blockIdx.y * 32;
    int tx = threadIdx.x & 31, ty = threadIdx.x >> 5;
    #pragma unroll
    for (int i = 0; i < 4; ++i)
        t[tx][ty + 8 * i] = in[(long)(k0 + ty + 8 * i) * DMM + n0 + tx];
    __syncthreads();
    #pragma unroll
    for (int i = 0; i < 4; ++i)
        out[(long)(n0 + ty + 8 * i) * DMM + k0 + tx] = f2b(t[ty + 8 * i][tx]);
}

// ---------------- layernorm: h fp32 -> hn bf16 ----------------------------
__global__ __launch_bounds__(256) void ln_k(const float* __restrict__ h,
                                            const float* __restrict__ g,
                                            const float* __restrict__ b,
                                            u16* __restrict__ hn) {
    int row = blockIdx.x, tid = threadIdx.x;
    const float* hr = h + (long)row * DMM;
    float x0 = hr[tid], x1 = hr[tid + 256], x2 = hr[tid + 512];
    float s = x0 + x1 + x2, sq = x0 * x0 + x1 * x1 + x2 * x2;
    #pragma unroll
    for (int m = 32; m > 0; m >>= 1) {
        s  += __shfl_xor(s,  m, 64);
        sq += __shfl_xor(sq, m, 64);
    }
    __shared__ float ls[4], lq[4];
    int w = tid >> 6;
    if ((tid & 63) == 0) { ls[w] = s; lq[w] = sq; }
    __syncthreads();
    s  = ls[0] + ls[1] + ls[2] + ls[3];
    sq = lq[0] + lq[1] + lq[2] + lq[3];
    float mean = s * (1.0f / DMM);
    float var  = fmaxf(sq * (1.0f / DMM) - mean * mean, 0.0f);
    float rs = rsqrtf(var + 1e-12f);
    u16* hnr = hn + (long)row * DMM;
    hnr[tid]       = f2b((x0 - mean) * rs * g[tid]       + b[tid]);
    hnr[tid + 256] = f2b((x1 - mean) * rs * g[tid + 256] + b[tid + 256]);
    hnr[tid + 512] = f2b((x2 - mean) * rs * g[tid + 512] + b[tid + 512]);
}

// ============= 256x256 8-phase GEMM: C[M][N] = A[M][K] @ BT[N][K]^T =======
// 8 waves (2M x 4N), BK=64, 2 LDS dbuf, XOR-swizzled LDS via pre-swizzled
// global source (rule 21). Per 4-phase window (1 K-tile): phase =
// {ds_read frags | stage 1 half-tile | barrier | lgkm(0) | 16 MFMA | barrier},
// counted vmcnt(4) once per window. Staging choreography:
//   window tau: ph0/1 stage A(tau+1)->dbuf^1 (opposite buffer, safe),
//               ph2/3 stage B(tau+2)->dbuf   (B(tau) consumed at ph0).
// EPI 0: out = acc + bias -> bf16 | 1: gelu -> bf16 | 2: h += (acc+bias)*lam
template <int EPI>
__global__ __launch_bounds__(512) void gemm256(
    const u16* __restrict__ A, const u16* __restrict__ BT,
    const float* __restrict__ bias, u16* __restrict__ outB,
    float* __restrict__ hio, const float* __restrict__ lam,
    int K, int N) {
    extern __shared__ __align__(16) u16 pool[];   // 131072 B dynamic
    int tid = threadIdx.x;
    int w = tid >> 6, lane = tid & 63;
    int wm = w >> 2, wn = w & 3;
    int m16 = lane & 15;
    int q = lane >> 4, kq4 = q * 4;
    int r7 = m16 & 7;

    // bijective XCD-chunked remap, n-fastest
    int nwg = gridDim.x, bid = blockIdx.x;
    int qd = nwg >> 3, rm = nwg & 7;
    int xcd = bid & 7, seq = bid >> 3;
    int wg = (xcd < rm ? xcd * (qd + 1) : rm * (qd + 1) + (xcd - rm) * qd) + seq;
    int ntn = N >> 8;
    long m0 = (long)(wg / ntn) * 256;
    long n0 = (long)(wg % ntn) * 256;

    // ds_read bases (bytes): A half = wm; swizzled slot = (kk*4+q)^r7
    int aK0 = wm * 16384 + m16 * 128 + ((q ^ r7) << 4);
    int aK1 = wm * 16384 + m16 * 128 + (((4 + q) ^ r7) << 4);
    int bK0 = 65536 + (wn >> 1) * 16384 + (((wn & 1) * 64 + m16) << 7) + ((q ^ r7) << 4);
    int bK1 = 65536 + (wn >> 1) * 16384 + (((wn & 1) * 64 + m16) << 7) + (((4 + q) ^ r7) << 4);

    // staging: thread covers LDS row lrow(+64*i), slot lane&7; global col-slot
    // pre-swizzled so linear gload_lds dest yields swizzled LDS layout.
    int lrow = (w << 3) | (lane >> 3);
    int colsw = ((lane & 7) ^ (lane >> 3)) << 3;
    const u16* gAr = A  + (m0 + lrow) * (long)K + colsw;
    const u16* gBr = BT + (n0 + lrow) * (long)K + colsw;
    u16* ldsA = pool + w * 512;
    u16* ldsB = pool + 32768 + w * 512;

#define STGA(d, h, kt) do {                                                 \
    const u16* s_ = gAr + (h) * 128 * (long)K + (kt) * 64;                  \
    gload16(s_,              ldsA + (d) * 16384 + (h) * 8192);              \
    gload16(s_ + 64 * (long)K, ldsA + (d) * 16384 + (h) * 8192 + 4096);     \
} while (0)
#define STGB(d, h, kt) do {                                                 \
    const u16* s_ = gBr + (h) * 128 * (long)K + (kt) * 64;                  \
    gload16(s_,              ldsB + (d) * 16384 + (h) * 8192);              \
    gload16(s_ + 64 * (long)K, ldsB + (d) * 16384 + (h) * 8192 + 4096);     \
} while (0)
#define RDA(d, fm, kk) (*(const bf16x8*)((const char*)pool + ((d) << 15) + aK##kk + (fm) * 2048))
#define RDB(d, fn, kk) (*(const bf16x8*)((const char*)pool + ((d) << 15) + bK##kk + (fn) * 2048))

    f32x4 acc[8][4] = {};
    bf16x8 bf[4][2];

#define PHASE(d, ph, DOA, ktA, DOB, ktB, VM) do {                           \
    if ((ph) == 0) {                                                        \
        _Pragma("unroll")                                                   \
        for (int fn = 0; fn < 4; ++fn) {                                    \
            bf[fn][0] = RDB(d, fn, 0);                                      \
            bf[fn][1] = RDB(d, fn, 1);                                      \
        }                                                                   \
    }                                                                       \
    bf16x8 a00 = RDA(d, 2 * (ph) + 0, 0), a01 = RDA(d, 2 * (ph) + 0, 1);    \
    bf16x8 a10 = RDA(d, 2 * (ph) + 1, 0), a11 = RDA(d, 2 * (ph) + 1, 1);    \
    if ((DOA) && (ph) == 0) STGA((d) ^ 1, 0, ktA);                          \
    if ((DOA) && (ph) == 1) STGA((d) ^ 1, 1, ktA);                          \
    if ((DOB) && (ph) == 2) STGB(d, 0, ktB);                                \
    if ((DOB) && (ph) == 3) STGB(d, 1, ktB);                                \
    __builtin_amdgcn_s_barrier();                                           \
    asm volatile("s_waitcnt lgkmcnt(0)" ::: "memory");                      \
    __builtin_amdgcn_sched_barrier(0);                                      \
    __builtin_amdgcn_s_setprio(1);                                          \
    _Pragma("unroll")                                                       \
    for (int fn = 0; fn < 4; ++fn) {                                        \
        acc[2*(ph)+0][fn] = __builtin_amdgcn_mfma_f32_16x16x32_bf16(a00, bf[fn][0], acc[2*(ph)+0][fn], 0, 0, 0); \
        acc[2*(ph)+0][fn] = __builtin_amdgcn_mfma_f32_16x16x32_bf16(a01, bf[fn][1], acc[2*(ph)+0][fn], 0, 0, 0); \
        acc[2*(ph)+1][fn] = __builtin_amdgcn_mfma_f32_16x16x32_bf16(a10, bf[fn][0], acc[2*(ph)+1][fn], 0, 0, 0); \
        acc[2*(ph)+1][fn] = __builtin_amdgcn_mfma_f32_16x16x32_bf16(a11, bf[fn][1], acc[2*(ph)+1][fn], 0, 0, 0); \
    }                                                                       \
    __builtin_amdgcn_s_setprio(0);                                          \
    if ((VM) == 4) asm volatile("s_waitcnt vmcnt(4)" ::: "memory");         \
    if ((VM) == 0) asm volatile("s_waitcnt vmcnt(0)" ::: "memory");         \
    __builtin_amdgcn_s_barrier();                                           \
} while (0)

#define WINDOW(d, ktA, DOA, ktB, DOB, VM)                                   \
    PHASE(d, 0, DOA, ktA, 0, 0, -1);                                        \
    PHASE(d, 1, DOA, ktA, 0, 0, -1);                                        \
    PHASE(d, 2, 0, 0, DOB, ktB, -1);                                        \
    PHASE(d, 3, 0, 0, DOB, ktB, VM);

    // prologue: tile0 (A+B) -> dbuf0, B(1) -> dbuf1; vmcnt(4) => tile0 landed
    STGA(0, 0, 0); STGA(0, 1, 0); STGB(0, 0, 0); STGB(0, 1, 0);
    STGB(1, 0, 1); STGB(1, 1, 1);
    asm volatile("s_waitcnt vmcnt(4)" ::: "memory");
    __builtin_amdgcn_s_barrier();

    const int nt = K >> 6;   // 12 or 48 (even, >= 4)
    for (int t = 0; t < nt - 2; t += 2) {
        WINDOW(0, t + 1, 1, t + 2, 1, 4);
        WINDOW(1, t + 2, 1, t + 3, 1, 4);
    }
    WINDOW(0, nt - 1, 1, 0, 0, 0);
    WINDOW(1, 0, 0, 0, 0, -1);

    // ---- epilogue: 2-pass [128][256] fp32 LDS stage, coalesced I/O -------
    float* Cs = (float*)pool;
    int colc = (tid & 63) * 4;
    int rb = tid >> 6;
    f32x4 bias4 = *(const f32x4*)&bias[n0 + colc];
    f32x4 lam4 = {};
    if (EPI == 2) lam4 = *(const f32x4*)&lam[n0 + colc];

    #pragma unroll
    for (int p2 = 0; p2 < 2; ++p2) {
        if (p2) hard_barrier();            // pass-0 readers done before overwrite
        if (wm == p2) {
            #pragma unroll
            for (int fm = 0; fm < 8; ++fm)
                #pragma unroll
                for (int fn = 0; fn < 4; ++fn)
                    #pragma unroll
                    for (int rr = 0; rr < 4; ++rr)
                        Cs[(fm * 16 + kq4 + rr) * 256 + wn * 64 + fn * 16 + m16] =
                            acc[fm][fn][rr];
        }
        hard_barrier();
        #pragma unroll
        for (int k = 0; k < 16; ++k) {
            int row = rb + k * 8;
            f32x4 v = *(const f32x4*)&Cs[row * 256 + colc];
            long gi = (m0 + p2 * 128 + row) * (long)N + n0 + colc;
            if (EPI == 0) {
                uint2 o;
                o.x = (unsigned)f2b(v[0] + bias4[0]) | ((unsigned)f2b(v[1] + bias4[1]) << 16);
                o.y = (unsigned)f2b(v[2] + bias4[2]) | ((unsigned)f2b(v[3] + bias4[3]) << 16);
                *(uint2*)&outB[gi] = o;
            } else if (EPI == 1) {
                uint2 o;
                o.x = (unsigned)f2b(gelu_exact(v[0] + bias4[0])) |
                      ((unsigned)f2b(gelu_exact(v[1] + bias4[1])) << 16);
                o.y = (unsigned)f2b(gelu_exact(v[2] + bias4[2])) |
                      ((unsigned)f2b(gelu_exact(v[3] + bias4[3])) << 16);
                *(uint2*)&outB[gi] = o;
            } else {
                f32x4 hv = *(f32x4*)&hio[gi];
                #pragma unroll
                for (int t4 = 0; t4 < 4; ++t4)
                    hv[t4] += (v[t4] + bias4[t4]) * lam4[t4];
                *(f32x4*)&hio[gi] = hv;
            }
        }
    }
#undef STGA
#undef STGB
#undef RDA
#undef RDB
#undef PHASE
#undef WINDOW
}

// ---------------- relative position bias index ----------------------------
__device__ __forceinline__ int relidx(int q, int k) {
    if (q == 0 && k == 0) return NDD - 1;
    if (k == 0) return NDD - 2;
    if (q == 0) return NDD - 3;
    int a = q - 1, c = k - 1;
    int dh = a / 14 - c / 14 + 13;
    int dw = a % 14 - c % 14 + 13;
    return dh * 27 + dw;
}

// -- precompute bias[h][208][208] fp32 + fused bqkv concat (one launch) ----
__global__ void bias_k(const float* __restrict__ rel, float* __restrict__ bias,
                       const float* __restrict__ bq, const float* __restrict__ bv,
                       float* __restrict__ bqkv) {
    int idx = blockIdx.x * 256 + threadIdx.x;
    if (idx < BIASN) {
        int hh = idx / (208 * 208);
        int r = (idx / 208) % 208, c = idx % 208;
        float v = 0.0f;
        if (r < SQ && c < SQ) v = rel[relidx(r, c) * NH + hh];
        bias[idx] = v;
    } else {
        int i = idx - BIASN;
        if (i < QS)
            bqkv[i] = (i < 768) ? bq[i] : ((i < 1536) ? 0.0f : bv[i - 1536]);
    }
}

// -------- attention part 1: S = QK^T * scale + bias, softmax -> P ---------
__global__ __launch_bounds__(256) void attn_qk(
    const u16* __restrict__ QKV, const float* __restrict__ bias,
    u16* __restrict__ P) {
    int bh = blockIdx.x;
    int b = bh / NH, hh = bh % NH;
    __shared__ u16 Ks[208 * KS2];
    int tid = threadIdx.x, w = tid >> 6, lane = tid & 63;
    long base = ((long)b * SQ) * QS + hh * HD;
    const u16* Qp = QKV;
    const u16* Kp = QKV + 768;
    u16* Pb = P + (long)bh * 208 * PCOLS;
    // zero P pad cols 208..223 (rows all written below)
    for (int idx = tid; idx < 208 * 16; idx += 256)
        Pb[(idx >> 4) * PCOLS + 208 + (idx & 15)] = 0;
    // stage K rows 0..207 (zeros beyond 196)
    for (int idx = tid; idx < 208 * 8; idx += 256) {
        int row = idx >> 3, dg = (idx & 7) * 8;
        us8 kv = {};
        if (row < SQ) kv = *(const us8*)&Kp[base + (long)row * QS + dg];
        *(us8*)&Ks[row * KS2 + dg] = kv;
    }
    __syncthreads();
    int m16 = lane & 15, quad = lane >> 4;
    int kq8 = quad * 8, q4 = quad * 4;
    const float* bh_bias = bias + (long)hh * 208 * 208;
    for (int t = w; t < 13; t += 4) {
        int m0 = t * 16;
        int qrow = m0 + m16; if (qrow > SQ - 1) qrow = SQ - 1;   // clamp pad rows
        bf16x8 a0 = *(const bf16x8*)&Qp[base + (long)qrow * QS + kq8];
        bf16x8 a1 = *(const bf16x8*)&Qp[base + (long)qrow * QS + 32 + kq8];
        f32x4 sc[13];
        #pragma unroll
        for (int n = 0; n < 13; ++n) {
            bf16x8 b0 = *(const bf16x8*)&Ks[(n * 16 + m16) * KS2 + kq8];
            bf16x8 b1 = *(const bf16x8*)&Ks[(n * 16 + m16) * KS2 + 32 + kq8];
            f32x4 z = {};
            z = __builtin_amdgcn_mfma_f32_16x16x32_bf16(a0, b0, z, 0, 0, 0);
            z = __builtin_amdgcn_mfma_f32_16x16x32_bf16(a1, b1, z, 0, 0, 0);
            sc[n] = z;
        }
        float mx[4] = {-3e38f, -3e38f, -3e38f, -3e38f};
        #pragma unroll
        for (int n = 0; n < 13; ++n) {
            int col = n * 16 + m16;
            bool valid = col < SQ;
            #pragma unroll
            for (int r = 0; r < 4; ++r) {
                float v = sc[n][r] * 0.125f + bh_bias[(m0 + q4 + r) * 208 + col];
                v = valid ? v : -3e38f;
                sc[n][r] = v;
                mx[r] = fmaxf(mx[r], v);
            }
        }
        #pragma unroll
        for (int r = 0; r < 4; ++r)
            #pragma unroll
            for (int msk = 1; msk < 16; msk <<= 1)
                mx[r] = fmaxf(mx[r], __shfl_xor(mx[r], msk, 64));
        float sum[4] = {0, 0, 0, 0};
        #pragma unroll
        for (int n = 0; n < 13; ++n)
            #pragma unroll
            for (int r = 0; r < 4; ++r) {
                float e = __expf(sc[n][r] - mx[r]);   // underflows to 0 when masked
                sc[n][r] = e;
                sum[r] += e;
            }
        #pragma unroll
        for (int r = 0; r < 4; ++r)
            #pragma unroll
            for (int msk = 1; msk < 16; msk <<= 1)
                sum[r] += __shfl_xor(sum[r], msk, 64);
        float inv[4];
        #pragma unroll
        for (int r = 0; r < 4; ++r) inv[r] = 1.0f / sum[r];
        #pragma unroll
        for (int n = 0; n < 13; ++n) {
            int col = n * 16 + m16;
            #pragma unroll
            for (int r = 0; r < 4; ++r)
                Pb[(m0 + q4 + r) * PCOLS + col] = f2b(sc[n][r] * inv[r]);
        }
    }
}

// -------- attention part 2: ctx = P @ V -----------------------------------
__global__ __launch_bounds__(256) void attn_pv(
    const u16* __restrict__ P, const u16* __restrict__ QKV,
    u16* __restrict__ ctx) {
    int bh = blockIdx.x;
    int b = bh / NH, hh = bh % NH;
    __shared__ u16 Vt[64 * VTS];   // Vt[d][k], zeros for k >= 197
    int tid = threadIdx.x, w = tid >> 6, lane = tid & 63;
    long base  = ((long)b * SQ) * QS + 1536 + hh * HD;
    long basec = ((long)b * SQ) * DMM + hh * HD;
    const u16* Vp = QKV;
    for (int idx = tid; idx < 224 * 8; idx += 256) {
        int row = idx >> 3, dg = (idx & 7) * 8;   // row = k index
        us8 vv = {};
        if (row < SQ) vv = *(const us8*)&Vp[base + (long)row * QS + dg];
        #pragma unroll
        for (int j = 0; j < 8; ++j) Vt[(dg + j) * VTS + row] = vv[j];
    }
    __syncthreads();
    const u16* Pb = P + (long)bh * 208 * PCOLS;
    int m16 = lane & 15, quad = lane >> 4;
    int kq8 = quad * 8, q4 = quad * 4;
    for (int t = w; t < 13; t += 4) {
        int m0 = t * 16;
        f32x4 co[4] = {};
        #pragma unroll
        for (int ks = 0; ks < 7; ++ks) {
            bf16x8 ap = *(const bf16x8*)&Pb[(m0 + m16) * PCOLS + ks * 32 + kq8];
            #pragma unroll
            for (int n = 0; n < 4; ++n) {
                bf16x8 bv = *(const bf16x8*)&Vt[(n * 16 + m16) * VTS + ks * 32 + kq8];
                co[n] = __builtin_amdgcn_mfma_f32_16x16x32_bf16(ap, bv, co[n], 0, 0, 0);
            }
        }
        #pragma unroll
        for (int n = 0; n < 4; ++n) {
            int col = n * 16 + m16;
            #pragma unroll
            for (int r = 0; r < 4; ++r) {
                int qr = m0 + q4 + r;
                if (qr < SQ) ctx[basec + (long)qr * DMM + col] = f2b(co[n][r]);
            }
        }
    }
}

// ---------------- host-side orchestration ---------------------------------
extern "C" void kernel_launch(void* const* d_in, const int* in_sizes, int n_in,
                              void* d_out, int out_size, void* d_ws, size_t ws_size,
                              hipStream_t stream) {
    const float* x    = (const float*)d_in[0];
    const float* cls  = (const float*)d_in[1];
    const float* g1   = (const float*)d_in[2];
    const float* b1   = (const float*)d_in[3];
    const float* Wq   = (const float*)d_in[4];
    const float* bq   = (const float*)d_in[5];
    const float* Wk   = (const float*)d_in[6];
    const float* Wv   = (const float*)d_in[7];
    const float* bv   = (const float*)d_in[8];
    const float* rel  = (const float*)d_in[9];
    const float* Wo   = (const float*)d_in[10];
    const float* bo   = (const float*)d_in[11];
    const float* lam1 = (const float*)d_in[12];
    const float* g2   = (const float*)d_in[13];
    const float* b2   = (const float*)d_in[14];
    const float* Wi   = (const float*)d_in[15];
    const float* bi   = (const float*)d_in[16];
    const float* Wmo  = (const float*)d_in[17];
    const float* bmo  = (const float*)d_in[18];
    const float* lam2 = (const float*)d_in[19];

    char* p = (char*)d_ws;
    auto alloc = [&](size_t bytes) -> void* {
        void* r = (void*)p;
        p += (bytes + 255) & ~(size_t)255;
        return r;
    };
    float* h     = (float*)alloc((size_t)MPAD * DMM * 4);
    u16*   hn    = (u16*)alloc((size_t)MPAD * DMM * 2);   // also reused as ctx
    u16*   qkvb  = (u16*)alloc((size_t)MPAD * QS * 2);    // fused Q|K|V
    u16*   ffh   = (u16*)alloc((size_t)MPAD * DFF * 2);   // also aliased as P
    u16*   WqkvT = (u16*)alloc((size_t)QS * DMM * 2);     // [2304][768]
    u16*   WoT   = (u16*)alloc((size_t)DMM * DMM * 2);
    u16*   WiT   = (u16*)alloc((size_t)DMM * DFF * 2);
    u16*   WmoT  = (u16*)alloc((size_t)DFF * DMM * 2);
    float* biasb = (float*)alloc((size_t)NH * 208 * 208 * 4);
    float* bqkv  = (float*)alloc((size_t)QS * 4);
    u16*   ctxb  = hn;   // alias: hn dead after QKV GEMM
    u16*   Pbuf  = ffh;  // alias: ffh dead during attention (71.6 MB <= 78.6 MB)

    patch_k<<<((long)MPAD * DMM + 255) / 256, 256, 0, stream>>>(x, cls, h);

    dim3 tg4(DMM / 32, DMM / 32, 4);
    dim3 tg2(DMM / 32, DFF / 32);
    dim3 tg3(DFF / 32, DMM / 32);
    int gqkv = (MPAD / 256) * (QS / 256);    // 50*9  = 450
    int g6   = (MPAD / 256) * (DMM / 256);   // 50*3  = 150
    int g24  = (MPAD / 256) * (DFF / 256);   // 50*12 = 600
    const size_t LDSB = 131072;

    for (int i = 0; i < 3; ++i) {
        size_t wofs  = (size_t)i * DMM * DMM;
        size_t wofs2 = (size_t)i * DMM * DFF;
        tcast4_k<<<tg4, 256, 0, stream>>>(Wq + wofs, Wk + wofs, Wv + wofs, Wo + wofs,
                                          WqkvT, WqkvT + 768 * DMM,
                                          WqkvT + 2 * 768 * DMM, WoT);
        tcast_k<<<tg2, 256, 0, stream>>>(Wi + wofs2, WiT, DMM, DFF);
        tcast_k<<<tg3, 256, 0, stream>>>(Wmo + wofs2, WmoT, DFF, DMM);
        bias_k<<<(BIASN + QS + 255) / 256, 256, 0, stream>>>(
            rel + (size_t)i * NDD * NH, biasb, bq + i * DMM, bv + i * DMM, bqkv);

        ln_k<<<MPAD, 256, 0, stream>>>(h, g1 + i * DMM, b1 + i * DMM, hn);
        gemm256<0><<<gqkv, 512, LDSB, stream>>>(hn, WqkvT, bqkv, qkvb, nullptr, nullptr, DMM, QS);
        attn_qk<<<BA * NH, 256, 0, stream>>>(qkvb, biasb, Pbuf);
        attn_pv<<<BA * NH, 256, 0, stream>>>(Pbuf, qkvb, ctxb);
        gemm256<2><<<g6, 512, LDSB, stream>>>(ctxb, WoT, bo + i * DMM, nullptr, h, lam1 + i * DMM, DMM, DMM);
        ln_k<<<MPAD, 256, 0, stream>>>(h, g2 + i * DMM, b2 + i * DMM, hn);
        gemm256<1><<<g24, 512, LDSB, stream>>>(hn, WiT, bi + i * DFF, ffh, nullptr, nullptr, DMM, DFF);
        gemm256<2><<<g6, 512, LDSB, stream>>>(ffh, WmoT, bmo + i * DMM, nullptr, h, lam2 + i * DMM, DFF, DMM);
    }

    out_k<<<((long)MROWS * DMM + 255) / 256, 256, 0, stream>>>(h, (float*)d_out);
}

// Round 5
// 1330.440 us; speedup vs baseline: 1.2667x; 1.0169x over previous
//
#include <hip/hip_runtime.h>

#define DMM 768
#define DFF 3072
#define NH  12
#define HD  64
#define SQ  197
#define BA  64
#define NDD 732
#define MROWS (BA*SQ)   // 12608
#define MPAD  12672     // 99*128
#define PCOLS 224       // padded k-dim for P (7 x 32)
#define KS2   72        // Ks LDS stride (16B-aligned rows, free 2-way banking)
#define VTS   232       // Vt / P-read stride
#define QS    2304      // fused QKV row stride
#define BIASN (NH*208*208)

typedef unsigned short u16;
typedef __bf16 bf16x8 __attribute__((ext_vector_type(8)));
typedef float  f32x4  __attribute__((ext_vector_type(4)));
typedef unsigned short us8 __attribute__((ext_vector_type(8)));

__device__ __forceinline__ u16 f2b(float f) {
    unsigned v; __builtin_memcpy(&v, &f, 4);
    unsigned r = v + 0x7FFFu + ((v >> 16) & 1u);
    return (u16)(r >> 16);
}
__device__ __forceinline__ float gelu_exact(float x) {
    return 0.5f * x * (1.0f + erff(x * 0.70710678118654752f));
}
__device__ __forceinline__ void gload16(const u16* g, u16* l) {
    __builtin_amdgcn_global_load_lds(
        (const __attribute__((address_space(1))) unsigned int*)(g),
        (__attribute__((address_space(3))) unsigned int*)(l), 16, 0, 0);
}
__device__ __forceinline__ void hard_barrier() {
    asm volatile("s_waitcnt lgkmcnt(0)" ::: "memory");
    __builtin_amdgcn_s_barrier();
}

// ------ fused patch embed + layer-0 layernorm: row-per-block --------------
// h[row] = raw embed (0 for pad rows); hn[row] = LN(h[row], g, b)
__global__ __launch_bounds__(256) void patchln_k(
    const float* __restrict__ x, const float* __restrict__ cls,
    const float* __restrict__ g, const float* __restrict__ b,
    float* __restrict__ h, u16* __restrict__ hn) {
    int row = blockIdx.x, tid = threadIdx.x;
    float x0 = 0.0f, x1 = 0.0f, x2 = 0.0f;
    if (row < MROWS) {
        int bb = row / SQ, s = row % SQ;
        const float* src = (s == 0) ? cls : &x[((long)bb * 196 + (s - 1)) * DMM];
        x0 = src[tid]; x1 = src[tid + 256]; x2 = src[tid + 512];
    }
    float* hr = h + (long)row * DMM;
    hr[tid] = x0; hr[tid + 256] = x1; hr[tid + 512] = x2;
    float s = x0 + x1 + x2, sq = x0 * x0 + x1 * x1 + x2 * x2;
    #pragma unroll
    for (int m = 32; m > 0; m >>= 1) {
        s  += __shfl_xor(s,  m, 64);
        sq += __shfl_xor(sq, m, 64);
    }
    __shared__ float ls[4], lq[4];
    int w = tid >> 6;
    if ((tid & 63) == 0) { ls[w] = s; lq[w] = sq; }
    __syncthreads();
    s  = ls[0] + ls[1] + ls[2] + ls[3];
    sq = lq[0] + lq[1] + lq[2] + lq[3];
    float mean = s * (1.0f / DMM);
    float var  = fmaxf(sq * (1.0f / DMM) - mean * mean, 0.0f);
    float rs = rsqrtf(var + 1e-12f);
    u16* hnr = hn + (long)row * DMM;
    hnr[tid]       = f2b((x0 - mean) * rs * g[tid]       + b[tid]);
    hnr[tid + 256] = f2b((x1 - mean) * rs * g[tid + 256] + b[tid + 256]);
    hnr[tid + 512] = f2b((x2 - mean) * rs * g[tid + 512] + b[tid + 512]);
}

// ------- fused transpose+cast: in fp32 [K][N] -> out bf16 [N][K] ----------
__global__ __launch_bounds__(256) void tcast_k(const float* __restrict__ in,
                                               u16* __restrict__ out,
                                               int Kd, int Nd) {
    __shared__ float t[32][33];
    int k0 = blockIdx.x * 32, n0 = blockIdx.y * 32;
    int tx = threadIdx.x & 31, ty = threadIdx.x >> 5;   // ty 0..7
    #pragma unroll
    for (int i = 0; i < 4; ++i)
        t[tx][ty + 8 * i] = in[(long)(k0 + ty + 8 * i) * Nd + n0 + tx];
    __syncthreads();
    #pragma unroll
    for (int i = 0; i < 4; ++i)
        out[(long)(n0 + ty + 8 * i) * Kd + k0 + tx] = f2b(t[ty + 8 * i][tx]);
}

// ------- 4x batched 768x768 transpose+cast (one launch per layer) ---------
__global__ __launch_bounds__(256) void tcast4_k(
    const float* __restrict__ s0, const float* __restrict__ s1,
    const float* __restrict__ s2, const float* __restrict__ s3,
    u16* __restrict__ d0, u16* __restrict__ d1,
    u16* __restrict__ d2, u16* __restrict__ d3) {
    __shared__ float t[32][33];
    int z = blockIdx.z;
    const float* in = (z == 0) ? s0 : (z == 1) ? s1 : (z == 2) ? s2 : s3;
    u16* out = (z == 0) ? d0 : (z == 1) ? d1 : (z == 2) ? d2 : d3;
    int k0 = blockIdx.x * 32, n0 = blockIdx.y * 32;
    int tx = threadIdx.x & 31, ty = threadIdx.x >> 5;
    #pragma unroll
    for (int i = 0; i < 4; ++i)
        t[tx][ty + 8 * i] = in[(long)(k0 + ty + 8 * i) * DMM + n0 + tx];
    __syncthreads();
    #pragma unroll
    for (int i = 0; i < 4; ++i)
        out[(long)(n0 + ty + 8 * i) * DMM + k0 + tx] = f2b(t[ty + 8 * i][tx]);
}

// ---------------- layernorm: h fp32 -> hn bf16 ----------------------------
__global__ __launch_bounds__(256) void ln_k(const float* __restrict__ h,
                                            const float* __restrict__ g,
                                            const float* __restrict__ b,
                                            u16* __restrict__ hn) {
    int row = blockIdx.x, tid = threadIdx.x;
    const float* hr = h + (long)row * DMM;
    float x0 = hr[tid], x1 = hr[tid + 256], x2 = hr[tid + 512];
    float s = x0 + x1 + x2, sq = x0 * x0 + x1 * x1 + x2 * x2;
    #pragma unroll
    for (int m = 32; m > 0; m >>= 1) {
        s  += __shfl_xor(s,  m, 64);
        sq += __shfl_xor(sq, m, 64);
    }
    __shared__ float ls[4], lq[4];
    int w = tid >> 6;
    if ((tid & 63) == 0) { ls[w] = s; lq[w] = sq; }
    __syncthreads();
    s  = ls[0] + ls[1] + ls[2] + ls[3];
    sq = lq[0] + lq[1] + lq[2] + lq[3];
    float mean = s * (1.0f / DMM);
    float var  = fmaxf(sq * (1.0f / DMM) - mean * mean, 0.0f);
    float rs = rsqrtf(var + 1e-12f);
    u16* hnr = hn + (long)row * DMM;
    hnr[tid]       = f2b((x0 - mean) * rs * g[tid]       + b[tid]);
    hnr[tid + 256] = f2b((x1 - mean) * rs * g[tid + 256] + b[tid + 256]);
    hnr[tid + 512] = f2b((x2 - mean) * rs * g[tid + 512] + b[tid + 512]);
}

// ---------------- GEMM: C[M][N] = A[M][K] @ B  (B given as BT[N][K]) ------
// r2 structure (empirically best): 2-buffer counted-vmcnt dist-1 pipeline,
// static unroll x2, 32 KB LDS -> 5 blocks/CU (max TLP; cross-block overlap
// is the latency-hiding mechanism at these small-tile shapes, m114).
// LDS-staged coalesced epilogue, XCD-chunked n-fastest block remap.
// EPI 0: out = acc + bias              -> bf16 outB
// EPI 1: out = gelu(acc + bias)        -> bf16 outB
// EPI 2: h   = h + (acc + bias) * lam  -> fp32 hio (in place)
//        (+ optional dual-write of updated rows < MROWS to hout)
template <int EPI>
__global__ __launch_bounds__(256) void gemm_bt(
    const u16* __restrict__ A, const u16* __restrict__ BT,
    const float* __restrict__ bias, u16* __restrict__ outB,
    float* __restrict__ hio, const float* __restrict__ lam,
    float* __restrict__ hout, int K, int N) {
    // 32768 B exactly: K-loop 2 x 16 KB buffers; epilogue overlays [64][128] f32
    __shared__ __align__(16) u16 pool[16384];
    int tid = threadIdx.x;
    int w = tid >> 6, lane = tid & 63;
    int wr = w >> 1, wc = w & 1;
    int m16 = lane & 15;
    int kq  = (lane >> 4) * 8;
    int kq4 = (lane >> 4) * 4;

    // bijective XCD-chunked remap (m204); n-tile fastest inside a chunk so
    // co-XCD blocks reuse the same 128-row A panel in their private L2.
    int nwg = gridDim.x, bid = blockIdx.x;
    int qd = nwg >> 3, rm = nwg & 7;
    int xcd = bid & 7, seq = bid >> 3;
    int wg = (xcd < rm ? xcd * (qd + 1) : rm * (qd + 1) + (xcd - rm) * qd) + seq;
    int ntn = N >> 7;
    long m0 = (long)(wg / ntn) * 128;
    long n0 = (long)(wg % ntn) * 128;

    f32x4 acc[4][4] = {};

    int row_a = tid >> 2;          // 0..63
    int col_a = (tid & 3) * 8;     // 0,8,16,24
    const u16* gA0 = &A[(m0 + row_a) * (long)K + col_a];
    const u16* gA1 = &A[(m0 + 64 + row_a) * (long)K + col_a];
    const u16* gB0 = &BT[(n0 + row_a) * (long)K + col_a];
    const u16* gB1 = &BT[(n0 + 64 + row_a) * (long)K + col_a];
    int wo = w * 512;              // per-wave LDS chunk (u16 units)

    u16* const b0 = pool;          // compile-time-constant buffer bases
    u16* const b1 = pool + 8192;

    auto stage = [&](int k, u16* buf) {
        int k0 = k << 5;
        gload16(gA0 + k0, buf + wo);
        gload16(gA1 + k0, buf + 2048 + wo);
        gload16(gB0 + k0, buf + 4096 + wo);
        gload16(gB1 + k0, buf + 6144 + wo);
    };
    auto compute = [&](const u16* buf) {
        bf16x8 af[4], bf[4];
        #pragma unroll
        for (int i = 0; i < 4; ++i)
            af[i] = *(const bf16x8*)&buf[(wr * 64 + i * 16 + m16) * 32 + kq];
        #pragma unroll
        for (int j = 0; j < 4; ++j)
            bf[j] = *(const bf16x8*)&buf[4096 + (wc * 64 + j * 16 + m16) * 32 + kq];
        #pragma unroll
        for (int i = 0; i < 4; ++i)
            #pragma unroll
            for (int j = 0; j < 4; ++j)
                acc[i][j] = __builtin_amdgcn_mfma_f32_16x16x32_bf16(
                    af[i], bf[j], acc[i][j], 0, 0, 0);
    };

    const int nsteps = K >> 5;     // even (24 or 96 here)
    stage(0, b0);
    for (int ks = 0; ks < nsteps - 2; ks += 2) {
        stage(ks + 1, b1);
        asm volatile("s_waitcnt vmcnt(4)" ::: "memory");  // stage(ks) landed
        __builtin_amdgcn_s_barrier();
        compute(b0);
        hard_barrier();            // all waves done reading b0
        stage(ks + 2, b0);
        asm volatile("s_waitcnt vmcnt(4)" ::: "memory");  // stage(ks+1) landed
        __builtin_amdgcn_s_barrier();
        compute(b1);
        hard_barrier();            // all waves done reading b1
    }
    // tail: steps nsteps-2 (staged into b0) and nsteps-1
    stage(nsteps - 1, b1);
    asm volatile("s_waitcnt vmcnt(4)" ::: "memory");
    __builtin_amdgcn_s_barrier();
    compute(b0);
    hard_barrier();
    asm volatile("s_waitcnt vmcnt(0)" ::: "memory");
    __builtin_amdgcn_s_barrier();
    compute(b1);

    // ---- epilogue: stage C tile through LDS (fp32), coalesced global I/O --
    hard_barrier();                        // all waves done with K-loop LDS
    float* Cs = (float*)pool;              // [64][128] fp32 = 32768 B
    float bcol[4];
    #pragma unroll
    for (int j = 0; j < 4; ++j)
        bcol[j] = bias ? bias[n0 + wc * 64 + j * 16 + m16] : 0.0f;
    int et4 = tid * 4;
    int colr = et4 & 127;                  // same col group for every k chunk
    f32x4 lam4 = {};
    if (EPI == 2) lam4 = *(const f32x4*)&lam[n0 + colr];

    #pragma unroll
    for (int p = 0; p < 2; ++p) {          // two 64-row half-tiles
        if (p) hard_barrier();             // pass-0 readers done before overwrite
        if (wr == p) {
            #pragma unroll
            for (int i = 0; i < 4; ++i)
                #pragma unroll
                for (int j = 0; j < 4; ++j)
                    #pragma unroll
                    for (int r = 0; r < 4; ++r)
                        Cs[(i * 16 + kq4 + r) * 128 + wc * 64 + j * 16 + m16] =
                            acc[i][j][r] + bcol[j];
        }
        hard_barrier();
        #pragma unroll
        for (int k = 0; k < 8; ++k) {
            int e0 = k * 1024 + et4;       // linear elem in 64x128 half-tile
            int row = e0 >> 7;
            f32x4 v = *(const f32x4*)&Cs[row * 128 + colr];
            long grow = m0 + p * 64 + row;
            long gi = grow * (long)N + n0 + colr;
            if (EPI == 0) {
                uint2 o;
                o.x = (unsigned)f2b(v[0]) | ((unsigned)f2b(v[1]) << 16);
                o.y = (unsigned)f2b(v[2]) | ((unsigned)f2b(v[3]) << 16);
                *(uint2*)&outB[gi] = o;
            } else if (EPI == 1) {
                uint2 o;
                o.x = (unsigned)f2b(gelu_exact(v[0])) | ((unsigned)f2b(gelu_exact(v[1])) << 16);
                o.y = (unsigned)f2b(gelu_exact(v[2])) | ((unsigned)f2b(gelu_exact(v[3])) << 16);
                *(uint2*)&outB[gi] = o;
            } else {
                f32x4 hv = *(f32x4*)&hio[gi];
                #pragma unroll
                for (int t = 0; t < 4; ++t) hv[t] += v[t] * lam4[t];
                *(f32x4*)&hio[gi] = hv;
                if (hout != nullptr && grow < MROWS)
                    *(f32x4*)&hout[gi] = hv;
            }
        }
    }
}

// ---------------- relative position bias index ----------------------------
__device__ __forceinline__ int relidx(int q, int k) {
    if (q == 0 && k == 0) return NDD - 1;
    if (k == 0) return NDD - 2;
    if (q == 0) return NDD - 3;
    int a = q - 1, c = k - 1;
    int dh = a / 14 - c / 14 + 13;
    int dw = a % 14 - c % 14 + 13;
    return dh * 27 + dw;
}

// -- precompute bias[h][208][208] fp32 + fused bqkv concat (one launch) ----
__global__ void bias_k(const float* __restrict__ rel, float* __restrict__ bias,
                       const float* __restrict__ bq, const float* __restrict__ bv,
                       float* __restrict__ bqkv) {
    int idx = blockIdx.x * 256 + threadIdx.x;
    if (idx < BIASN) {
        int hh = idx / (208 * 208);
        int r = (idx / 208) % 208, c = idx % 208;
        float v = 0.0f;
        if (r < SQ && c < SQ) v = rel[relidx(r, c) * NH + hh];
        bias[idx] = v;
    } else {
        int i = idx - BIASN;
        if (i < QS)
            bqkv[i] = (i < 768) ? bq[i] : ((i < 1536) ? 0.0f : bv[i - 1536]);
    }
}

// -------- attention part 1: S = QK^T * scale + bias, softmax -> P ---------
__global__ __launch_bounds__(256) void attn_qk(
    const u16* __restrict__ QKV, const float* __restrict__ bias,
    u16* __restrict__ P) {
    int bh = blockIdx.x;
    int b = bh / NH, hh = bh % NH;
    __shared__ u16 Ks[208 * KS2];
    int tid = threadIdx.x, w = tid >> 6, lane = tid & 63;
    long base = ((long)b * SQ) * QS + hh * HD;
    const u16* Qp = QKV;
    const u16* Kp = QKV + 768;
    u16* Pb = P + (long)bh * 208 * PCOLS;
    // zero P pad cols 208..223 (rows all written below)
    for (int idx = tid; idx < 208 * 16; idx += 256)
        Pb[(idx >> 4) * PCOLS + 208 + (idx & 15)] = 0;
    // stage K rows 0..207 (zeros beyond 196)
    for (int idx = tid; idx < 208 * 8; idx += 256) {
        int row = idx >> 3, dg = (idx & 7) * 8;
        us8 kv = {};
        if (row < SQ) kv = *(const us8*)&Kp[base + (long)row * QS + dg];
        *(us8*)&Ks[row * KS2 + dg] = kv;
    }
    __syncthreads();
    int m16 = lane & 15, quad = lane >> 4;
    int kq8 = quad * 8, q4 = quad * 4;
    const float* bh_bias = bias + (long)hh * 208 * 208;
    for (int t = w; t < 13; t += 4) {
        int m0 = t * 16;
        int qrow = m0 + m16; if (qrow > SQ - 1) qrow = SQ - 1;   // clamp pad rows
        bf16x8 a0 = *(const bf16x8*)&Qp[base + (long)qrow * QS + kq8];
        bf16x8 a1 = *(const bf16x8*)&Qp[base + (long)qrow * QS + 32 + kq8];
        f32x4 sc[13];
        #pragma unroll
        for (int n = 0; n < 13; ++n) {
            bf16x8 b0 = *(const bf16x8*)&Ks[(n * 16 + m16) * KS2 + kq8];
            bf16x8 b1 = *(const bf16x8*)&Ks[(n * 16 + m16) * KS2 + 32 + kq8];
            f32x4 z = {};
            z = __builtin_amdgcn_mfma_f32_16x16x32_bf16(a0, b0, z, 0, 0, 0);
            z = __builtin_amdgcn_mfma_f32_16x16x32_bf16(a1, b1, z, 0, 0, 0);
            sc[n] = z;
        }
        float mx[4] = {-3e38f, -3e38f, -3e38f, -3e38f};
        #pragma unroll
        for (int n = 0; n < 13; ++n) {
            int col = n * 16 + m16;
            bool valid = col < SQ;
            #pragma unroll
            for (int r = 0; r < 4; ++r) {
                float v = sc[n][r] * 0.125f + bh_bias[(m0 + q4 + r) * 208 + col];
                v = valid ? v : -3e38f;
                sc[n][r] = v;
                mx[r] = fmaxf(mx[r], v);
            }
        }
        #pragma unroll
        for (int r = 0; r < 4; ++r)
            #pragma unroll
            for (int msk = 1; msk < 16; msk <<= 1)
                mx[r] = fmaxf(mx[r], __shfl_xor(mx[r], msk, 64));
        float sum[4] = {0, 0, 0, 0};
        #pragma unroll
        for (int n = 0; n < 13; ++n)
            #pragma unroll
            for (int r = 0; r < 4; ++r) {
                float e = __expf(sc[n][r] - mx[r]);   // underflows to 0 when masked
                sc[n][r] = e;
                sum[r] += e;
            }
        #pragma unroll
        for (int r = 0; r < 4; ++r)
            #pragma unroll
            for (int msk = 1; msk < 16; msk <<= 1)
                sum[r] += __shfl_xor(sum[r], msk, 64);
        float inv[4];
        #pragma unroll
        for (int r = 0; r < 4; ++r) inv[r] = 1.0f / sum[r];
        #pragma unroll
        for (int n = 0; n < 13; ++n) {
            int col = n * 16 + m16;
            #pragma unroll
            for (int r = 0; r < 4; ++r)
                Pb[(m0 + q4 + r) * PCOLS + col] = f2b(sc[n][r] * inv[r]);
        }
    }
}

// -------- attention part 2: ctx = P @ V -----------------------------------
__global__ __launch_bounds__(256) void attn_pv(
    const u16* __restrict__ P, const u16* __restrict__ QKV,
    u16* __restrict__ ctx) {
    int bh = blockIdx.x;
    int b = bh / NH, hh = bh % NH;
    __shared__ u16 Vt[64 * VTS];   // Vt[d][k], zeros for k >= 197
    int tid = threadIdx.x, w = tid >> 6, lane = tid & 63;
    long base  = ((long)b * SQ) * QS + 1536 + hh * HD;
    long basec = ((long)b * SQ) * DMM + hh * HD;
    const u16* Vp = QKV;
    for (int idx = tid; idx < 224 * 8; idx += 256) {
        int row = idx >> 3, dg = (idx & 7) * 8;   // row = k index
        us8 vv = {};
        if (row < SQ) vv = *(const us8*)&Vp[base + (long)row * QS + dg];
        #pragma unroll
        for (int j = 0; j < 8; ++j) Vt[(dg + j) * VTS + row] = vv[j];
    }
    __syncthreads();
    const u16* Pb = P + (long)bh * 208 * PCOLS;
    int m16 = lane & 15, quad = lane >> 4;
    int kq8 = quad * 8, q4 = quad * 4;
    for (int t = w; t < 13; t += 4) {
        int m0 = t * 16;
        f32x4 co[4] = {};
        #pragma unroll
        for (int ks = 0; ks < 7; ++ks) {
            bf16x8 ap = *(const bf16x8*)&Pb[(m0 + m16) * PCOLS + ks * 32 + kq8];
            #pragma unroll
            for (int n = 0; n < 4; ++n) {
                bf16x8 bv = *(const bf16x8*)&Vt[(n * 16 + m16) * VTS + ks * 32 + kq8];
                co[n] = __builtin_amdgcn_mfma_f32_16x16x32_bf16(ap, bv, co[n], 0, 0, 0);
            }
        }
        #pragma unroll
        for (int n = 0; n < 4; ++n) {
            int col = n * 16 + m16;
            #pragma unroll
            for (int r = 0; r < 4; ++r) {
                int qr = m0 + q4 + r;
                if (qr < SQ) ctx[basec + (long)qr * DMM + col] = f2b(co[n][r]);
            }
        }
    }
}

// ---------------- host-side orchestration ---------------------------------
extern "C" void kernel_launch(void* const* d_in, const int* in_sizes, int n_in,
                              void* d_out, int out_size, void* d_ws, size_t ws_size,
                              hipStream_t stream) {
    const float* x    = (const float*)d_in[0];
    const float* cls  = (const float*)d_in[1];
    const float* g1   = (const float*)d_in[2];
    const float* b1   = (const float*)d_in[3];
    const float* Wq   = (const float*)d_in[4];
    const float* bq   = (const float*)d_in[5];
    const float* Wk   = (const float*)d_in[6];
    const float* Wv   = (const float*)d_in[7];
    const float* bv   = (const float*)d_in[8];
    const float* rel  = (const float*)d_in[9];
    const float* Wo   = (const float*)d_in[10];
    const float* bo   = (const float*)d_in[11];
    const float* lam1 = (const float*)d_in[12];
    const float* g2   = (const float*)d_in[13];
    const float* b2   = (const float*)d_in[14];
    const float* Wi   = (const float*)d_in[15];
    const float* bi   = (const float*)d_in[16];
    const float* Wmo  = (const float*)d_in[17];
    const float* bmo  = (const float*)d_in[18];
    const float* lam2 = (const float*)d_in[19];

    char* p = (char*)d_ws;
    auto alloc = [&](size_t bytes) -> void* {
        void* r = (void*)p;
        p += (bytes + 255) & ~(size_t)255;
        return r;
    };
    float* h     = (float*)alloc((size_t)MPAD * DMM * 4);
    u16*   hn    = (u16*)alloc((size_t)MPAD * DMM * 2);   // also reused as ctx
    u16*   qkvb  = (u16*)alloc((size_t)MPAD * QS * 2);    // fused Q|K|V
    u16*   ffh   = (u16*)alloc((size_t)MPAD * DFF * 2);   // also aliased as P
    u16*   WqkvT = (u16*)alloc((size_t)QS * DMM * 2);     // [2304][768]
    u16*   WoT   = (u16*)alloc((size_t)DMM * DMM * 2);
    u16*   WiT   = (u16*)alloc((size_t)DMM * DFF * 2);
    u16*   WmoT  = (u16*)alloc((size_t)DFF * DMM * 2);
    float* biasb = (float*)alloc((size_t)NH * 208 * 208 * 4);
    float* bqkv  = (float*)alloc((size_t)QS * 4);
    u16*   ctxb  = hn;   // alias: hn dead after QKV GEMM
    u16*   Pbuf  = ffh;  // alias: ffh dead during attention (71.6 MB <= 77.9 MB)

    dim3 tg4(DMM / 32, DMM / 32, 4);
    dim3 tg2(DMM / 32, DFF / 32);
    dim3 tg3(DFF / 32, DMM / 32);
    int gqkv = (MPAD / 128) * (QS / 128);    // 99*18 = 1782
    int g6   = (MPAD / 128) * (DMM / 128);   // 99*6  = 594
    int g24  = (MPAD / 128) * (DFF / 128);   // 99*24 = 2376

    // fused patch embed + layer-0 LN
    patchln_k<<<MPAD, 256, 0, stream>>>(x, cls, g1, b1, h, hn);

    for (int i = 0; i < 3; ++i) {
        size_t wofs  = (size_t)i * DMM * DMM;
        size_t wofs2 = (size_t)i * DMM * DFF;
        tcast4_k<<<tg4, 256, 0, stream>>>(Wq + wofs, Wk + wofs, Wv + wofs, Wo + wofs,
                                          WqkvT, WqkvT + 768 * DMM,
                                          WqkvT + 2 * 768 * DMM, WoT);
        tcast_k<<<tg2, 256, 0, stream>>>(Wi + wofs2, WiT, DMM, DFF);
        tcast_k<<<tg3, 256, 0, stream>>>(Wmo + wofs2, WmoT, DFF, DMM);
        bias_k<<<(BIASN + QS + 255) / 256, 256, 0, stream>>>(
            rel + (size_t)i * NDD * NH, biasb, bq + i * DMM, bv + i * DMM, bqkv);

        if (i > 0)
            ln_k<<<MPAD, 256, 0, stream>>>(h, g1 + i * DMM, b1 + i * DMM, hn);
        gemm_bt<0><<<gqkv, 256, 0, stream>>>(hn, WqkvT, bqkv, qkvb, nullptr, nullptr, nullptr, DMM, QS);
        attn_qk<<<BA * NH, 256, 0, stream>>>(qkvb, biasb, Pbuf);
        attn_pv<<<BA * NH, 256, 0, stream>>>(Pbuf, qkvb, ctxb);
        gemm_bt<2><<<g6, 256, 0, stream>>>(ctxb, WoT, bo + i * DMM, nullptr, h, lam1 + i * DMM, nullptr, DMM, DMM);
        ln_k<<<MPAD, 256, 0, stream>>>(h, g2 + i * DMM, b2 + i * DMM, hn);
        gemm_bt<1><<<g24, 256, 0, stream>>>(hn, WiT, bi + i * DFF, ffh, nullptr, nullptr, nullptr, DMM, DFF);
        gemm_bt<2><<<g6, 256, 0, stream>>>(ffh, WmoT, bmo + i * DMM, nullptr, h, lam2 + i * DMM,
                                           (i == 2) ? (float*)d_out : nullptr, DFF, DMM);
    }
}